// Round 7
// baseline (2116.022 us; speedup 1.0000x reference)
//
#include <hip/hip_runtime.h>
#include <cmath>

#define NNODES 50000
#define NEDGES 800000
#define ORIG_FEA 92
#define NBR_FEA 41
#define HID 64
#define BN_EPS 1e-5f
#define ECOLS 48          // eab_s columns: 41 real + 7 pad

typedef __attribute__((ext_vector_type(8))) short short8;
typedef __attribute__((ext_vector_type(4))) float f32x4;
typedef unsigned short ushort;
typedef unsigned int uint;

static __device__ __forceinline__ ushort f2bf(float f) {
    uint u = __float_as_uint(f);
    uint r = u + 0x7fffu + ((u >> 16) & 1u);   // round-to-nearest-even
    return (ushort)(r >> 16);
}

// ---------------------------------------------------------------------------
// prep_embed: all input-only setup in ONE launch (deg zeroed by memset first).
//  blocks 0..23      : Bpack/Tpack/bias packing (6 groups x 4 quarters)
//  block  24         : zero BN stats
//  blocks 25..3149   : k_hist (800K edges, atomics on deg)
//  blocks 3150..4173 : embed h = x @ W1 + b1 (coalesced x load + shfl bcast)
// ---------------------------------------------------------------------------
#define HIST_BASE 25
#define HIST_BLOCKS 3125
#define EMBED_BASE (HIST_BASE + HIST_BLOCKS)   // 3150
#define EMBED_BLOCKS 1024

__global__ __launch_bounds__(256) void prep_embed(
    const float* __restrict__ W2, const float* __restrict__ b2,
    const float* __restrict__ Wf, const float* __restrict__ bf,
    const float* __restrict__ Ws, const float* __restrict__ bs,
    ushort* __restrict__ Bpack, ushort* __restrict__ Tpack,
    float* __restrict__ bcf, float* __restrict__ bcs,
    float* __restrict__ stats, int* __restrict__ deg,
    const int* __restrict__ eidx,
    const float* __restrict__ x, const float* __restrict__ W1,
    const float* __restrict__ b1, float* __restrict__ h,
    ushort* __restrict__ h_bf) {
    if (blockIdx.x >= EMBED_BASE) {
        int lane = threadIdx.x & 63;
        int wid = (((int)blockIdx.x - EMBED_BASE) * 256 + (int)threadIdx.x) >> 6;
        int nw = (EMBED_BLOCKS * 256) >> 6;
        float b1v = b1[lane];
        for (int n = wid; n < NNODES; n += nw) {
            const float* xr = x + (long)n * ORIG_FEA;
            float xa = xr[lane];
            float xb = (lane < ORIG_FEA - 64) ? xr[64 + lane] : 0.f;
            float a0 = b1v, a1 = 0.f, a2 = 0.f, a3 = 0.f;
            #pragma unroll
            for (int k = 0; k < 64; k += 4) {
                a0 = fmaf(__shfl(xa, k, 64),     W1[k * HID + lane], a0);
                a1 = fmaf(__shfl(xa, k + 1, 64), W1[(k + 1) * HID + lane], a1);
                a2 = fmaf(__shfl(xa, k + 2, 64), W1[(k + 2) * HID + lane], a2);
                a3 = fmaf(__shfl(xa, k + 3, 64), W1[(k + 3) * HID + lane], a3);
            }
            #pragma unroll
            for (int k = 0; k < ORIG_FEA - 64; k += 4) {
                a0 = fmaf(__shfl(xb, k, 64),     W1[(64 + k) * HID + lane], a0);
                a1 = fmaf(__shfl(xb, k + 1, 64), W1[(65 + k) * HID + lane], a1);
                a2 = fmaf(__shfl(xb, k + 2, 64), W1[(66 + k) * HID + lane], a2);
                a3 = fmaf(__shfl(xb, k + 3, 64), W1[(67 + k) * HID + lane], a3);
            }
            float acc = (a0 + a1) + (a2 + a3);
            h[(long)n * HID + lane] = acc;
            h_bf[(long)n * HID + lane] = f2bf(acc);
        }
        return;
    }
    if (blockIdx.x >= HIST_BASE) {
        int e = ((int)blockIdx.x - HIST_BASE) * 256 + (int)threadIdx.x;
        if (e < NEDGES) atomicAdd(&deg[eidx[NEDGES + e]], 1);
        return;
    }
    if (blockIdx.x == 24) {
        for (int i = threadIdx.x; i < 3 * 128; i += blockDim.x) stats[i] = 0.f;
        return;
    }
    // blocks 0..23: weight packing
    int group = blockIdx.x >> 2;       // 0..5 = (layer, fs)
    int quarter = blockIdx.x & 3;
    int layer = group >> 1;
    int fs = group & 1;
    const float* Wbig = (fs ? Ws : Wf) + layer * 192 * HID;
    const float* We = Wbig + 128 * HID;                 // e-part rows
    const float* bvec = (fs ? bs : bf) + layer * HID;
    float* bc = (fs ? bcs : bcf) + layer * HID;
    ushort* Bp = Bpack + layer * 16384 + fs * 8192;     // t = fs*4 + tt
    ushort* Tp = Tpack + layer * 8192 + fs * 4096;

    for (int idx = quarter * 2048 + threadIdx.x; idx < (quarter + 1) * 2048;
         idx += blockDim.x) {
        int j = idx & 7;
        int lane = (idx >> 3) & 63;
        int ck = (idx >> 9) & 3;
        int tt = (idx >> 11) & 3;
        int k = ck * 32 + ((lane >> 4) * 8) + j;
        int col = tt * 16 + (lane & 15);
        float v = 0.f;
        if (k < 64) v = Wbig[(64 + k) * HID + col];
        else if (k < 64 + NBR_FEA) {
            int r = k - 64;
            float a = 0.f;
            for (int m = 0; m < HID; ++m) a += W2[r * HID + m] * We[m * HID + col];
            v = a;
        }
        Bp[(tt * 4 + ck) * 512 + lane * 8 + j] = f2bf(v);
    }
    // target-block B fragments (K=64), quarter-split
    for (int idx = quarter * 1024 + threadIdx.x; idx < (quarter + 1) * 1024;
         idx += blockDim.x) {
        int j = idx & 7;
        int lane = (idx >> 3) & 63;
        int ck = (idx >> 9) & 1;
        int t = (idx >> 10) & 3;
        int k = ck * 32 + ((lane >> 4) * 8) + j;
        int col = t * 16 + (lane & 15);
        Tp[(t * 2 + ck) * 512 + lane * 8 + j] = f2bf(Wbig[k * HID + col]);
    }
    if (quarter == 3) {
        for (int c0 = threadIdx.x; c0 < HID; c0 += blockDim.x) {
            float a = bvec[c0];
            for (int m = 0; m < HID; ++m) a += b2[m] * We[m * HID + c0];
            bc[c0] = a;
        }
    }
}

// ---------------------------------------------------------------------------
// CSR scan kernels
// ---------------------------------------------------------------------------
__global__ void k_blocksum(const int* __restrict__ deg, int* __restrict__ bsum) {
    __shared__ int sh[256];
    int i = blockIdx.x * 256 + threadIdx.x;
    sh[threadIdx.x] = (i < NNODES) ? deg[i] : 0;
    __syncthreads();
    for (int s = 128; s > 0; s >>= 1) {
        if (threadIdx.x < s) sh[threadIdx.x] += sh[threadIdx.x + s];
        __syncthreads();
    }
    if (threadIdx.x == 0) bsum[blockIdx.x] = sh[0];
}

__global__ void k_scanbase(const int* __restrict__ bsum, int* __restrict__ bbase,
                           int* __restrict__ rowptr) {
    __shared__ int sh[256];
    int t = threadIdx.x;
    int v = (t < 196) ? bsum[t] : 0;
    sh[t] = v;
    __syncthreads();
    for (int s = 1; s < 256; s <<= 1) {
        int add = (t >= s) ? sh[t - s] : 0;
        __syncthreads();
        sh[t] += add;
        __syncthreads();
    }
    if (t < 196) bbase[t] = sh[t] - v;   // exclusive
    if (t == 0) rowptr[NNODES] = NEDGES;
}

__global__ void k_writerow(const int* __restrict__ deg, const int* __restrict__ bbase,
                           int* __restrict__ rowptr, int* __restrict__ cursor) {
    __shared__ int sh[256];
    int t = threadIdx.x;
    int i = blockIdx.x * 256 + t;
    int v = (i < NNODES) ? deg[i] : 0;
    sh[t] = v;
    __syncthreads();
    for (int s = 1; s < 256; s <<= 1) {
        int add = (t >= s) ? sh[t - s] : 0;
        __syncthreads();
        sh[t] += add;
        __syncthreads();
    }
    if (i < NNODES) {
        int e = bbase[blockIdx.x] + sh[t] - v;
        rowptr[i] = e;
        cursor[i] = e;
    }
}

// ---------------------------------------------------------------------------
// scat_proj: one launch, two independent jobs.
//  blocks < 3125 : CSR scatter + eab row build (thread-per-edge; 41 ea loads
//                  issued before the atomic; 96 B row write to slot pos)
//  blocks >= 3125: layer-0 proj_mfma (Ttgt = h_bf @ W_tgt + bc)
// ---------------------------------------------------------------------------
#define SCAT_BLOCKS 3125
#define PROJ_BLOCKS 1024

__global__ __launch_bounds__(256) void scat_proj(
    const int* __restrict__ eidx, int* __restrict__ cursor,
    int* __restrict__ srcs, const float* __restrict__ ea,
    ushort* __restrict__ eab_s,
    const ushort* __restrict__ h_bf, const ushort* __restrict__ Tpack_l,
    const float* __restrict__ bcf_l, const float* __restrict__ bcs_l,
    float* __restrict__ Ttgt) {
    if (blockIdx.x < SCAT_BLOCKS) {
        int e = blockIdx.x * 256 + threadIdx.x;
        if (e >= NEDGES) return;
        const float* row = ea + (long)e * NBR_FEA;
        float a[NBR_FEA];
        #pragma unroll
        for (int k = 0; k < NBR_FEA; ++k) a[k] = row[k];
        int tgt = eidx[NEDGES + e];
        int pos = atomicAdd(&cursor[tgt], 1);
        srcs[pos] = eidx[e];
        uint u[24];
        #pragma unroll
        for (int m = 0; m < 20; ++m)
            u[m] = (uint)f2bf(a[2 * m]) | ((uint)f2bf(a[2 * m + 1]) << 16);
        u[20] = (uint)f2bf(a[40]);
        u[21] = 0u; u[22] = 0u; u[23] = 0u;
        uint4* dst = (uint4*)(eab_s + (long)pos * ECOLS);
        #pragma unroll
        for (int m = 0; m < 6; ++m) {
            uint4 o; o.x = u[4 * m]; o.y = u[4 * m + 1];
            o.z = u[4 * m + 2]; o.w = u[4 * m + 3];
            dst[m] = o;
        }
        return;
    }
    // ---- proj branch ----
    int lane = threadIdx.x & 63;
    int cc = lane & 15;
    int g = lane >> 4;
    short8 Bf[4][2], Bs[4][2];
    #pragma unroll
    for (int t = 0; t < 4; ++t)
        #pragma unroll
        for (int ck = 0; ck < 2; ++ck) {
            Bf[t][ck] = *(const short8*)(Tpack_l + (t * 2 + ck) * 512 + lane * 8);
            Bs[t][ck] = *(const short8*)(Tpack_l + 4096 + (t * 2 + ck) * 512 + lane * 8);
        }
    float bfv[4], bsv[4];
    #pragma unroll
    for (int t = 0; t < 4; ++t) {
        bfv[t] = bcf_l[t * 16 + cc];
        bsv[t] = bcs_l[t * 16 + cc];
    }
    int wid = (((int)blockIdx.x - SCAT_BLOCKS) * 256 + (int)threadIdx.x) >> 6;
    int nw = (PROJ_BLOCKS * 256) >> 6;
    for (int nb = wid; nb < NNODES / 16; nb += nw) {
        long base = (long)nb * 16;
        long row = base + cc;
        short8 A0 = *(const short8*)(h_bf + row * 64 + g * 8);
        short8 A1 = *(const short8*)(h_bf + row * 64 + 32 + g * 8);
        f32x4 accf[4], accs[4];
        f32x4 z4 = {0.f, 0.f, 0.f, 0.f};
        #pragma unroll
        for (int t = 0; t < 4; ++t) {
            accf[t] = __builtin_amdgcn_mfma_f32_16x16x32_bf16(A0, Bf[t][0], z4, 0, 0, 0);
            accs[t] = __builtin_amdgcn_mfma_f32_16x16x32_bf16(A0, Bs[t][0], z4, 0, 0, 0);
        }
        #pragma unroll
        for (int t = 0; t < 4; ++t) {
            accf[t] = __builtin_amdgcn_mfma_f32_16x16x32_bf16(A1, Bf[t][1], accf[t], 0, 0, 0);
            accs[t] = __builtin_amdgcn_mfma_f32_16x16x32_bf16(A1, Bs[t][1], accs[t], 0, 0, 0);
        }
        #pragma unroll
        for (int r = 0; r < 4; ++r) {
            long node = base + g * 4 + r;
            f32x4 vf = {accf[0][r] + bfv[0], accf[1][r] + bfv[1],
                        accf[2][r] + bfv[2], accf[3][r] + bfv[3]};
            f32x4 vs = {accs[0][r] + bsv[0], accs[1][r] + bsv[1],
                        accs[2][r] + bsv[2], accs[3][r] + bsv[3]};
            *(f32x4*)(Ttgt + node * 128 + cc * 4) = vf;
            *(f32x4*)(Ttgt + node * 128 + 64 + cc * 4) = vs;
        }
    }
}

// ---------------------------------------------------------------------------
// Edge kernel: one wave per target, chunk-ahead pipeline. THIS ROUND: B lives
// in LDS (32 KB) instead of 128 registers -> total VGPR <= 128 -> 4 waves/SIMD
// (was 2). ds_read_b128 per MFMA overlaps the matrix pipe; doubled TLP hides
// the h_bf/eab gather latency the 1-deep pipeline couldn't.
// ---------------------------------------------------------------------------
#define BL(t, ck) (*(const short8*)(Bl + (((t) * 4 + (ck)) * 512 + lane * 8)))

__global__ __launch_bounds__(256, 4) void edge_kernel(
    const ushort* __restrict__ eab_s, const int* __restrict__ srcs,
    const int* __restrict__ rowptr, const ushort* __restrict__ h_bf,
    const float* __restrict__ h, const float* __restrict__ Ttgt,
    const ushort* __restrict__ Bpack, float* __restrict__ agg,
    float* __restrict__ stats) {
    __shared__ ushort Bl[16384];          // 32 KB: same layout as Bpack
    __shared__ float ls[4][64], lq[4][64];
    for (int i = threadIdx.x; i < 2048; i += 256)
        ((uint4*)Bl)[i] = ((const uint4*)Bpack)[i];
    __syncthreads();

    int lane = threadIdx.x & 63;
    int q = lane >> 4;
    int c = lane & 15;
    int wid = (blockIdx.x * blockDim.x + threadIdx.x) >> 6;
    int nw = (gridDim.x * blockDim.x) >> 6;
    const short8 z8 = {0, 0, 0, 0, 0, 0, 0, 0};

    float st1 = 0.f, st2 = 0.f;
    int tn = wid;
    int r0 = 0, r1 = 0, svAll = 0;
    short8 A0, A1, A2, A3;
    if (tn < NNODES) {
        r0 = rowptr[tn]; r1 = rowptr[tn + 1];
        int e = r0 + lane; if (e > NEDGES - 1) e = NEDGES - 1;
        svAll = srcs[e];
        int sv = __shfl(svAll, c, 64);
        int ei = r0 + c; if (ei > NEDGES - 1) ei = NEDGES - 1;
        const short8* hrow = (const short8*)(h_bf + (long)sv * 64);
        const ushort* erow = eab_s + (long)ei * ECOLS;
        A0 = hrow[q]; A1 = hrow[4 + q];
        A2 = *(const short8*)(erow + q * 8);
        A3 = z8;
        if (q < 2) A3 = *(const short8*)(erow + 32 + q * 8);
    }

    while (tn < NNODES) {
        int tn2 = tn + nw;
        int r0n = 0, r1n = 0;
        if (tn2 < NNODES) { r0n = rowptr[tn2]; r1n = rowptr[tn2 + 1]; }
        f32x4 tf = *(const f32x4*)(Ttgt + (long)tn * 128 + 4 * c);
        f32x4 ts = *(const f32x4*)(Ttgt + (long)tn * 128 + 64 + 4 * c);
        int d = r1 - r0;
        int nch = (d + 15) >> 4;
        float vs0 = 0.f, vs1 = 0.f, vs2 = 0.f, vs3 = 0.f;

        if (nch == 0) {
            // isolated node: still prefetch next target's chunk 0
            int e = r0n + lane; if (e > NEDGES - 1) e = NEDGES - 1;
            svAll = srcs[e];
            int sv = __shfl(svAll, c, 64);
            int ei = r0n + c; if (ei > NEDGES - 1) ei = NEDGES - 1;
            const short8* hrow = (const short8*)(h_bf + (long)sv * 64);
            const ushort* erow = eab_s + (long)ei * ECOLS;
            A0 = hrow[q]; A1 = hrow[4 + q];
            A2 = *(const short8*)(erow + q * 8);
            A3 = z8;
            if (q < 2) A3 = *(const short8*)(erow + 32 + q * 8);
        } else {
            for (int ci = 0; ci < nch; ++ci) {
                // ---- issue prefetch for chunk ci+1 (or next target's chunk 0)
                int sv, ei;
                int nidx = ci + 1;
                if (nidx < nch) {
                    if ((nidx & 3) == 0) {       // superchunk boundary (d>64, rare)
                        int e = r0 + nidx * 16 + lane;
                        if (e > NEDGES - 1) e = NEDGES - 1;
                        svAll = srcs[e];
                    }
                    sv = __shfl(svAll, ((nidx & 3) << 4) + c, 64);
                    ei = r0 + nidx * 16 + c;
                    if (ei > NEDGES - 1) ei = NEDGES - 1;
                } else {
                    int e = r0n + lane; if (e > NEDGES - 1) e = NEDGES - 1;
                    svAll = srcs[e];
                    sv = __shfl(svAll, c, 64);
                    ei = r0n + c; if (ei > NEDGES - 1) ei = NEDGES - 1;
                }
                const short8* hrow = (const short8*)(h_bf + (long)sv * 64);
                const ushort* erow = eab_s + (long)ei * ECOLS;
                short8 N0 = hrow[q], N1 = hrow[4 + q];
                short8 N2 = *(const short8*)(erow + q * 8);
                short8 N3 = z8;
                if (q < 2) N3 = *(const short8*)(erow + 32 + q * 8);

                // ---- compute current chunk (A resident; B from LDS) ----
                f32x4 accf[4], accs[4];
                f32x4 z4 = {0.f, 0.f, 0.f, 0.f};
                __builtin_amdgcn_s_setprio(1);
                #pragma unroll
                for (int t = 0; t < 4; ++t) {
                    accf[t] = __builtin_amdgcn_mfma_f32_16x16x32_bf16(A0, BL(t, 0), z4, 0, 0, 0);
                    accs[t] = __builtin_amdgcn_mfma_f32_16x16x32_bf16(A0, BL(t + 4, 0), z4, 0, 0, 0);
                }
                #pragma unroll
                for (int t = 0; t < 4; ++t) {
                    accf[t] = __builtin_amdgcn_mfma_f32_16x16x32_bf16(A1, BL(t, 1), accf[t], 0, 0, 0);
                    accs[t] = __builtin_amdgcn_mfma_f32_16x16x32_bf16(A1, BL(t + 4, 1), accs[t], 0, 0, 0);
                }
                #pragma unroll
                for (int t = 0; t < 4; ++t) {
                    accf[t] = __builtin_amdgcn_mfma_f32_16x16x32_bf16(A2, BL(t, 2), accf[t], 0, 0, 0);
                    accs[t] = __builtin_amdgcn_mfma_f32_16x16x32_bf16(A2, BL(t + 4, 2), accs[t], 0, 0, 0);
                }
                #pragma unroll
                for (int t = 0; t < 4; ++t) {
                    accf[t] = __builtin_amdgcn_mfma_f32_16x16x32_bf16(A3, BL(t, 3), accf[t], 0, 0, 0);
                    accs[t] = __builtin_amdgcn_mfma_f32_16x16x32_bf16(A3, BL(t + 4, 3), accs[t], 0, 0, 0);
                }
                __builtin_amdgcn_s_setprio(0);

                int base = ci * 16 + q * 4;
                #pragma unroll
                for (int r = 0; r < 4; ++r) {
                    bool valid = (base + r) < d;
                    #pragma unroll
                    for (int t = 0; t < 4; ++t) {
                        float f = accf[t][r] + tf[t];
                        float s = accs[t][r] + ts[t];
                        float g = __builtin_amdgcn_rcpf(1.f + __expf(-f));
                        float sp = fmaxf(s, 0.f) + __logf(1.f + __expf(-fabsf(s)));
                        float msg = valid ? g * sp : 0.f;
                        if (t == 0) vs0 += msg;
                        else if (t == 1) vs1 += msg;
                        else if (t == 2) vs2 += msg;
                        else vs3 += msg;
                    }
                }
                A0 = N0; A1 = N1; A2 = N2; A3 = N3;
            }
        }
        vs0 += __shfl_xor(vs0, 16, 64); vs0 += __shfl_xor(vs0, 32, 64);
        vs1 += __shfl_xor(vs1, 16, 64); vs1 += __shfl_xor(vs1, 32, 64);
        vs2 += __shfl_xor(vs2, 16, 64); vs2 += __shfl_xor(vs2, 32, 64);
        vs3 += __shfl_xor(vs3, 16, 64); vs3 += __shfl_xor(vs3, 32, 64);
        float out = (q == 0) ? vs0 : (q == 1) ? vs1 : (q == 2) ? vs2 : vs3;
        agg[(long)tn * 64 + lane] = out;           // channel = q*16+c = lane
        float v = h[(long)tn * 64 + lane] + out;
        st1 += v;
        st2 = fmaf(v, v, st2);

        tn = tn2; r0 = r0n; r1 = r1n;
    }

    // block-level stats reduction -> 2 atomics/lane/block
    int w = threadIdx.x >> 6;
    ls[w][lane] = st1; lq[w][lane] = st2;
    __syncthreads();
    if (threadIdx.x < 64) {
        float t1 = ls[0][lane] + ls[1][lane] + ls[2][lane] + ls[3][lane];
        float t2 = lq[0][lane] + lq[1][lane] + lq[2][lane] + lq[3][lane];
        atomicAdd(&stats[lane], t1);
        atomicAdd(&stats[64 + lane], t2);
    }
}

// ---------------------------------------------------------------------------
// bnproj: BN apply (+ReLU) fused with NEXT layer's target projection.
// ---------------------------------------------------------------------------
__global__ __launch_bounds__(256) void bnproj(
    float* __restrict__ h, const float* __restrict__ agg,
    const float* __restrict__ stats, const float* __restrict__ gamma,
    const float* __restrict__ beta, ushort* __restrict__ h_bf,
    const ushort* __restrict__ Tpack_l, const float* __restrict__ bcf_l,
    const float* __restrict__ bcs_l, float* __restrict__ Ttgt) {
    int lane = threadIdx.x & 63;
    int cc = lane & 15;
    int g = lane >> 4;
    short8 Bf[4][2], Bs[4][2];
    #pragma unroll
    for (int t = 0; t < 4; ++t)
        #pragma unroll
        for (int ck = 0; ck < 2; ++ck) {
            Bf[t][ck] = *(const short8*)(Tpack_l + (t * 2 + ck) * 512 + lane * 8);
            Bs[t][ck] = *(const short8*)(Tpack_l + 4096 + (t * 2 + ck) * 512 + lane * 8);
        }
    float bfv[4], bsv[4];
    #pragma unroll
    for (int t = 0; t < 4; ++t) {
        bfv[t] = bcf_l[t * 16 + cc];
        bsv[t] = bcs_l[t * 16 + cc];
    }
    const float invn = 1.f / (float)NNODES;
    float sc[16], sh[16];
    #pragma unroll
    for (int m = 0; m < 16; ++m) {
        int ch = (m < 8) ? (g * 8 + m) : (32 + g * 8 + (m - 8));
        float mu = stats[ch] * invn;
        float va = stats[64 + ch] * invn - mu * mu;
        float s = rsqrtf(va + BN_EPS) * gamma[ch];
        sc[m] = s;
        sh[m] = beta[ch] - mu * s;
    }
    int wid = (blockIdx.x * blockDim.x + threadIdx.x) >> 6;
    int nw = (gridDim.x * blockDim.x) >> 6;
    for (int nb = wid; nb < NNODES / 16; nb += nw) {
        long base = (long)nb * 16;
        long row = base + cc;
        float* hr = h + row * 64;
        const float* ar = agg + row * 64;
        float y[16];
        #pragma unroll
        for (int half = 0; half < 2; ++half) {
            int col = half * 32 + g * 8;
            f32x4 hv0 = *(const f32x4*)(hr + col);
            f32x4 hv1 = *(const f32x4*)(hr + col + 4);
            f32x4 av0 = *(const f32x4*)(ar + col);
            f32x4 av1 = *(const f32x4*)(ar + col + 4);
            #pragma unroll
            for (int m = 0; m < 4; ++m) {
                float t0 = (hv0[m] + av0[m]) * sc[half * 8 + m] + sh[half * 8 + m];
                float t1 = (hv1[m] + av1[m]) * sc[half * 8 + 4 + m] + sh[half * 8 + 4 + m];
                y[half * 8 + m] = fmaxf(t0, 0.f);        // relu (layers 0,1 only)
                y[half * 8 + 4 + m] = fmaxf(t1, 0.f);
            }
        }
        f32x4 w0 = {y[0], y[1], y[2], y[3]},   w1 = {y[4], y[5], y[6], y[7]};
        f32x4 w2 = {y[8], y[9], y[10], y[11]}, w3 = {y[12], y[13], y[14], y[15]};
        *(f32x4*)(hr + g * 8) = w0;       *(f32x4*)(hr + g * 8 + 4) = w1;
        *(f32x4*)(hr + 32 + g * 8) = w2;  *(f32x4*)(hr + 32 + g * 8 + 4) = w3;
        uint u[8];
        #pragma unroll
        for (int m = 0; m < 8; ++m)
            u[m] = (uint)f2bf(y[m * 2]) | ((uint)f2bf(y[m * 2 + 1]) << 16);
        uint4 p0; p0.x = u[0]; p0.y = u[1]; p0.z = u[2]; p0.w = u[3];
        uint4 p1; p1.x = u[4]; p1.y = u[5]; p1.z = u[6]; p1.w = u[7];
        *(uint4*)(h_bf + row * 64 + g * 8) = p0;
        *(uint4*)(h_bf + row * 64 + 32 + g * 8) = p1;
        short8 A0 = *reinterpret_cast<short8*>(&p0);
        short8 A1 = *reinterpret_cast<short8*>(&p1);

        f32x4 accf[4], accs[4];
        f32x4 z4 = {0.f, 0.f, 0.f, 0.f};
        #pragma unroll
        for (int t = 0; t < 4; ++t) {
            accf[t] = __builtin_amdgcn_mfma_f32_16x16x32_bf16(A0, Bf[t][0], z4, 0, 0, 0);
            accs[t] = __builtin_amdgcn_mfma_f32_16x16x32_bf16(A0, Bs[t][0], z4, 0, 0, 0);
        }
        #pragma unroll
        for (int t = 0; t < 4; ++t) {
            accf[t] = __builtin_amdgcn_mfma_f32_16x16x32_bf16(A1, Bf[t][1], accf[t], 0, 0, 0);
            accs[t] = __builtin_amdgcn_mfma_f32_16x16x32_bf16(A1, Bs[t][1], accs[t], 0, 0, 0);
        }
        #pragma unroll
        for (int r = 0; r < 4; ++r) {
            long node = base + g * 4 + r;
            f32x4 vf = {accf[0][r] + bfv[0], accf[1][r] + bfv[1],
                        accf[2][r] + bfv[2], accf[3][r] + bfv[3]};
            f32x4 vs = {accs[0][r] + bsv[0], accs[1][r] + bsv[1],
                        accs[2][r] + bsv[2], accs[3][r] + bsv[3]};
            *(f32x4*)(Ttgt + node * 128 + cc * 4) = vf;
            *(f32x4*)(Ttgt + node * 128 + 64 + cc * 4) = vs;
        }
    }
}

// ---------------------------------------------------------------------------
// bn_final: last layer BN (no relu, no h_bf, no proj). Pure streaming.
// ---------------------------------------------------------------------------
__global__ __launch_bounds__(256) void bn_final(
    float* __restrict__ h, const float* __restrict__ agg,
    const float* __restrict__ stats, const float* __restrict__ gamma,
    const float* __restrict__ beta) {
    int tid = blockIdx.x * blockDim.x + threadIdx.x;
    int nth = gridDim.x * blockDim.x;   // multiple of 16
    const float invn = 1.f / (float)NNODES;
    int cb = (tid & 15) * 4;
    f32x4 sc, sh;
    #pragma unroll
    for (int j = 0; j < 4; ++j) {
        float m = stats[cb + j] * invn;
        float v = stats[64 + cb + j] * invn - m * m;
        float s = rsqrtf(v + BN_EPS) * gamma[cb + j];
        sc[j] = s;
        sh[j] = beta[cb + j] - m * s;
    }
    for (long i = tid; i < (long)NNODES * 16; i += nth) {
        f32x4 v = ((const f32x4*)h)[i];
        f32x4 a = ((const f32x4*)agg)[i];
        f32x4 y;
        #pragma unroll
        for (int j = 0; j < 4; ++j) y[j] = (v[j] + a[j]) * sc[j] + sh[j];
        ((f32x4*)h)[i] = y;
    }
}

extern "C" void kernel_launch(void* const* d_in, const int* in_sizes, int n_in,
                              void* d_out, int out_size, void* d_ws, size_t ws_size,
                              hipStream_t stream) {
    const float* x    = (const float*)d_in[0];
    const float* ea   = (const float*)d_in[1];
    const int*   eidx = (const int*)d_in[2];
    const float* W1   = (const float*)d_in[3];
    const float* b1   = (const float*)d_in[4];
    const float* W2   = (const float*)d_in[5];
    const float* b2   = (const float*)d_in[6];
    const float* Wf   = (const float*)d_in[7];
    const float* bf   = (const float*)d_in[8];
    const float* Ws   = (const float*)d_in[9];
    const float* bs   = (const float*)d_in[10];
    const float* gamma= (const float*)d_in[11];
    const float* beta = (const float*)d_in[12];
    float* h = (float*)d_out; // [NNODES, 64]

    // workspace layout (256 B aligned sections)
    char* wb = (char*)d_ws;
    auto align = [&]() { wb = (char*)(((size_t)wb + 255) & ~(size_t)255); };
    ushort* Bpack = (ushort*)wb;  wb += 3 * 8 * 4 * 512 * sizeof(ushort); align(); // 96 KB
    ushort* Tpack = (ushort*)wb;  wb += 3 * 2 * 4 * 2 * 512 * sizeof(ushort); align(); // 48 KB
    float* bcf   = (float*)wb;    wb += 3 * HID * sizeof(float);
    float* bcs   = (float*)wb;    wb += 3 * HID * sizeof(float);
    float* stats = (float*)wb;    wb += 3 * 2 * HID * sizeof(float); align();
    int* deg     = (int*)wb;      wb += NNODES * sizeof(int);
    int* rowptr  = (int*)wb;      wb += (NNODES + 1) * sizeof(int);
    int* cursor  = (int*)wb;      wb += NNODES * sizeof(int);
    int* bsum    = (int*)wb;      wb += 256 * sizeof(int);
    int* bbase   = (int*)wb;      wb += 256 * sizeof(int); align();
    int* srcs    = (int*)wb;      wb += NEDGES * sizeof(int);          // 3.2 MB
    align();
    float* Ttgt  = (float*)wb;    wb += (size_t)NNODES * 128 * sizeof(float); // 25.6 MB
    float* agg   = (float*)wb;    wb += (size_t)NNODES * HID * sizeof(float); // 12.8 MB
    ushort* h_bf = (ushort*)wb;   wb += (size_t)NNODES * HID * sizeof(ushort); // 6.4 MB
    ushort* eab_s= (ushort*)wb;   wb += (size_t)NEDGES * ECOLS * sizeof(ushort); // 76.8 MB

    // --- setup ---
    hipMemsetAsync(deg, 0, NNODES * sizeof(int), stream);
    prep_embed<<<EMBED_BASE + EMBED_BLOCKS, 256, 0, stream>>>(
        W2, b2, Wf, bf, Ws, bs, Bpack, Tpack, bcf, bcs, stats, deg, eidx,
        x, W1, b1, h, h_bf);
    k_blocksum<<<196, 256, 0, stream>>>(deg, bsum);
    k_scanbase<<<1, 256, 0, stream>>>(bsum, bbase, rowptr);
    k_writerow<<<196, 256, 0, stream>>>(deg, bbase, rowptr, cursor);
    scat_proj<<<SCAT_BLOCKS + PROJ_BLOCKS, 256, 0, stream>>>(
        eidx, cursor, srcs, ea, eab_s, h_bf, Tpack, bcf, bcs, Ttgt);

    for (int i = 0; i < 3; ++i) {
        edge_kernel<<<2048, 256, 0, stream>>>(eab_s, srcs, rowptr, h_bf, h, Ttgt,
                                              Bpack + i * 16384, agg, stats + i * 128);
        if (i < 2)
            bnproj<<<1024, 256, 0, stream>>>(h, agg, stats + i * 128, gamma + i * HID,
                                             beta + i * HID, h_bf,
                                             Tpack + (i + 1) * 8192,
                                             bcf + (i + 1) * HID, bcs + (i + 1) * HID,
                                             Ttgt);
        else
            bn_final<<<2048, 256, 0, stream>>>(h, agg, stats + i * 128,
                                               gamma + i * HID, beta + i * HID);
    }
}

// Round 8
// 1515.690 us; speedup vs baseline: 1.3961x; 1.3961x over previous
//
#include <hip/hip_runtime.h>
#include <cmath>

#define NNODES 50000
#define NEDGES 800000
#define ORIG_FEA 92
#define NBR_FEA 41
#define HID 64
#define BN_EPS 1e-5f
#define ECOLS 48          // eab_s columns: 41 real + 7 pad

typedef __attribute__((ext_vector_type(8))) short short8;
typedef __attribute__((ext_vector_type(4))) float f32x4;
typedef unsigned short ushort;
typedef unsigned int uint;

static __device__ __forceinline__ ushort f2bf(float f) {
    uint u = __float_as_uint(f);
    uint r = u + 0x7fffu + ((u >> 16) & 1u);   // round-to-nearest-even
    return (ushort)(r >> 16);
}

// ---------------------------------------------------------------------------
// prep_embed: all input-only setup in ONE launch (deg zeroed by memset first).
//  blocks 0..23      : Bpack/Tpack/bias packing (6 groups x 4 quarters)
//  block  24         : zero BN stats
//  blocks 25..3149   : k_hist (800K edges, atomics on deg)
//  blocks 3150..4173 : embed h = x @ W1 + b1 (coalesced x load + shfl bcast)
// ---------------------------------------------------------------------------
#define HIST_BASE 25
#define HIST_BLOCKS 3125
#define EMBED_BASE (HIST_BASE + HIST_BLOCKS)   // 3150
#define EMBED_BLOCKS 1024

__global__ __launch_bounds__(256) void prep_embed(
    const float* __restrict__ W2, const float* __restrict__ b2,
    const float* __restrict__ Wf, const float* __restrict__ bf,
    const float* __restrict__ Ws, const float* __restrict__ bs,
    ushort* __restrict__ Bpack, ushort* __restrict__ Tpack,
    float* __restrict__ bcf, float* __restrict__ bcs,
    float* __restrict__ stats, int* __restrict__ deg,
    const int* __restrict__ eidx,
    const float* __restrict__ x, const float* __restrict__ W1,
    const float* __restrict__ b1, float* __restrict__ h,
    ushort* __restrict__ h_bf) {
    if (blockIdx.x >= EMBED_BASE) {
        int lane = threadIdx.x & 63;
        int wid = (((int)blockIdx.x - EMBED_BASE) * 256 + (int)threadIdx.x) >> 6;
        int nw = (EMBED_BLOCKS * 256) >> 6;
        float b1v = b1[lane];
        for (int n = wid; n < NNODES; n += nw) {
            const float* xr = x + (long)n * ORIG_FEA;
            float xa = xr[lane];
            float xb = (lane < ORIG_FEA - 64) ? xr[64 + lane] : 0.f;
            float a0 = b1v, a1 = 0.f, a2 = 0.f, a3 = 0.f;
            #pragma unroll
            for (int k = 0; k < 64; k += 4) {
                a0 = fmaf(__shfl(xa, k, 64),     W1[k * HID + lane], a0);
                a1 = fmaf(__shfl(xa, k + 1, 64), W1[(k + 1) * HID + lane], a1);
                a2 = fmaf(__shfl(xa, k + 2, 64), W1[(k + 2) * HID + lane], a2);
                a3 = fmaf(__shfl(xa, k + 3, 64), W1[(k + 3) * HID + lane], a3);
            }
            #pragma unroll
            for (int k = 0; k < ORIG_FEA - 64; k += 4) {
                a0 = fmaf(__shfl(xb, k, 64),     W1[(64 + k) * HID + lane], a0);
                a1 = fmaf(__shfl(xb, k + 1, 64), W1[(65 + k) * HID + lane], a1);
                a2 = fmaf(__shfl(xb, k + 2, 64), W1[(66 + k) * HID + lane], a2);
                a3 = fmaf(__shfl(xb, k + 3, 64), W1[(67 + k) * HID + lane], a3);
            }
            float acc = (a0 + a1) + (a2 + a3);
            h[(long)n * HID + lane] = acc;
            h_bf[(long)n * HID + lane] = f2bf(acc);
        }
        return;
    }
    if (blockIdx.x >= HIST_BASE) {
        int e = ((int)blockIdx.x - HIST_BASE) * 256 + (int)threadIdx.x;
        if (e < NEDGES) atomicAdd(&deg[eidx[NEDGES + e]], 1);
        return;
    }
    if (blockIdx.x == 24) {
        for (int i = threadIdx.x; i < 3 * 128; i += blockDim.x) stats[i] = 0.f;
        return;
    }
    // blocks 0..23: weight packing
    int group = blockIdx.x >> 2;       // 0..5 = (layer, fs)
    int quarter = blockIdx.x & 3;
    int layer = group >> 1;
    int fs = group & 1;
    const float* Wbig = (fs ? Ws : Wf) + layer * 192 * HID;
    const float* We = Wbig + 128 * HID;                 // e-part rows
    const float* bvec = (fs ? bs : bf) + layer * HID;
    float* bc = (fs ? bcs : bcf) + layer * HID;
    ushort* Bp = Bpack + layer * 16384 + fs * 8192;     // t = fs*4 + tt
    ushort* Tp = Tpack + layer * 8192 + fs * 4096;

    for (int idx = quarter * 2048 + threadIdx.x; idx < (quarter + 1) * 2048;
         idx += blockDim.x) {
        int j = idx & 7;
        int lane = (idx >> 3) & 63;
        int ck = (idx >> 9) & 3;
        int tt = (idx >> 11) & 3;
        int k = ck * 32 + ((lane >> 4) * 8) + j;
        int col = tt * 16 + (lane & 15);
        float v = 0.f;
        if (k < 64) v = Wbig[(64 + k) * HID + col];
        else if (k < 64 + NBR_FEA) {
            int r = k - 64;
            float a = 0.f;
            for (int m = 0; m < HID; ++m) a += W2[r * HID + m] * We[m * HID + col];
            v = a;
        }
        Bp[(tt * 4 + ck) * 512 + lane * 8 + j] = f2bf(v);
    }
    // target-block B fragments (K=64), quarter-split
    for (int idx = quarter * 1024 + threadIdx.x; idx < (quarter + 1) * 1024;
         idx += blockDim.x) {
        int j = idx & 7;
        int lane = (idx >> 3) & 63;
        int ck = (idx >> 9) & 1;
        int t = (idx >> 10) & 3;
        int k = ck * 32 + ((lane >> 4) * 8) + j;
        int col = t * 16 + (lane & 15);
        Tp[(t * 2 + ck) * 512 + lane * 8 + j] = f2bf(Wbig[k * HID + col]);
    }
    if (quarter == 3) {
        for (int c0 = threadIdx.x; c0 < HID; c0 += blockDim.x) {
            float a = bvec[c0];
            for (int m = 0; m < HID; ++m) a += b2[m] * We[m * HID + c0];
            bc[c0] = a;
        }
    }
}

// ---------------------------------------------------------------------------
// CSR scan kernels
// ---------------------------------------------------------------------------
__global__ void k_blocksum(const int* __restrict__ deg, int* __restrict__ bsum) {
    __shared__ int sh[256];
    int i = blockIdx.x * 256 + threadIdx.x;
    sh[threadIdx.x] = (i < NNODES) ? deg[i] : 0;
    __syncthreads();
    for (int s = 128; s > 0; s >>= 1) {
        if (threadIdx.x < s) sh[threadIdx.x] += sh[threadIdx.x + s];
        __syncthreads();
    }
    if (threadIdx.x == 0) bsum[blockIdx.x] = sh[0];
}

__global__ void k_scanbase(const int* __restrict__ bsum, int* __restrict__ bbase,
                           int* __restrict__ rowptr) {
    __shared__ int sh[256];
    int t = threadIdx.x;
    int v = (t < 196) ? bsum[t] : 0;
    sh[t] = v;
    __syncthreads();
    for (int s = 1; s < 256; s <<= 1) {
        int add = (t >= s) ? sh[t - s] : 0;
        __syncthreads();
        sh[t] += add;
        __syncthreads();
    }
    if (t < 196) bbase[t] = sh[t] - v;   // exclusive
    if (t == 0) rowptr[NNODES] = NEDGES;
}

__global__ void k_writerow(const int* __restrict__ deg, const int* __restrict__ bbase,
                           int* __restrict__ rowptr, int* __restrict__ cursor) {
    __shared__ int sh[256];
    int t = threadIdx.x;
    int i = blockIdx.x * 256 + t;
    int v = (i < NNODES) ? deg[i] : 0;
    sh[t] = v;
    __syncthreads();
    for (int s = 1; s < 256; s <<= 1) {
        int add = (t >= s) ? sh[t - s] : 0;
        __syncthreads();
        sh[t] += add;
        __syncthreads();
    }
    if (i < NNODES) {
        int e = bbase[blockIdx.x] + sh[t] - v;
        rowptr[i] = e;
        cursor[i] = e;
    }
}

// ---------------------------------------------------------------------------
// scat_proj: one launch, two independent jobs.
//  blocks < 3125 : CSR scatter + eab row build (thread-per-edge; 41 ea loads
//                  issued before the atomic; 96 B row write to slot pos)
//  blocks >= 3125: layer-0 proj_mfma (Ttgt = h_bf @ W_tgt + bc)
// ---------------------------------------------------------------------------
#define SCAT_BLOCKS 3125
#define PROJ_BLOCKS 1024

__global__ __launch_bounds__(256) void scat_proj(
    const int* __restrict__ eidx, int* __restrict__ cursor,
    int* __restrict__ srcs, const float* __restrict__ ea,
    ushort* __restrict__ eab_s,
    const ushort* __restrict__ h_bf, const ushort* __restrict__ Tpack_l,
    const float* __restrict__ bcf_l, const float* __restrict__ bcs_l,
    float* __restrict__ Ttgt) {
    if (blockIdx.x < SCAT_BLOCKS) {
        int e = blockIdx.x * 256 + threadIdx.x;
        if (e >= NEDGES) return;
        const float* row = ea + (long)e * NBR_FEA;
        float a[NBR_FEA];
        #pragma unroll
        for (int k = 0; k < NBR_FEA; ++k) a[k] = row[k];
        int tgt = eidx[NEDGES + e];
        int pos = atomicAdd(&cursor[tgt], 1);
        srcs[pos] = eidx[e];
        uint u[24];
        #pragma unroll
        for (int m = 0; m < 20; ++m)
            u[m] = (uint)f2bf(a[2 * m]) | ((uint)f2bf(a[2 * m + 1]) << 16);
        u[20] = (uint)f2bf(a[40]);
        u[21] = 0u; u[22] = 0u; u[23] = 0u;
        uint4* dst = (uint4*)(eab_s + (long)pos * ECOLS);
        #pragma unroll
        for (int m = 0; m < 6; ++m) {
            uint4 o; o.x = u[4 * m]; o.y = u[4 * m + 1];
            o.z = u[4 * m + 2]; o.w = u[4 * m + 3];
            dst[m] = o;
        }
        return;
    }
    // ---- proj branch ----
    int lane = threadIdx.x & 63;
    int cc = lane & 15;
    int g = lane >> 4;
    short8 Bf[4][2], Bs[4][2];
    #pragma unroll
    for (int t = 0; t < 4; ++t)
        #pragma unroll
        for (int ck = 0; ck < 2; ++ck) {
            Bf[t][ck] = *(const short8*)(Tpack_l + (t * 2 + ck) * 512 + lane * 8);
            Bs[t][ck] = *(const short8*)(Tpack_l + 4096 + (t * 2 + ck) * 512 + lane * 8);
        }
    float bfv[4], bsv[4];
    #pragma unroll
    for (int t = 0; t < 4; ++t) {
        bfv[t] = bcf_l[t * 16 + cc];
        bsv[t] = bcs_l[t * 16 + cc];
    }
    int wid = (((int)blockIdx.x - SCAT_BLOCKS) * 256 + (int)threadIdx.x) >> 6;
    int nw = (PROJ_BLOCKS * 256) >> 6;
    for (int nb = wid; nb < NNODES / 16; nb += nw) {
        long base = (long)nb * 16;
        long row = base + cc;
        short8 A0 = *(const short8*)(h_bf + row * 64 + g * 8);
        short8 A1 = *(const short8*)(h_bf + row * 64 + 32 + g * 8);
        f32x4 accf[4], accs[4];
        f32x4 z4 = {0.f, 0.f, 0.f, 0.f};
        #pragma unroll
        for (int t = 0; t < 4; ++t) {
            accf[t] = __builtin_amdgcn_mfma_f32_16x16x32_bf16(A0, Bf[t][0], z4, 0, 0, 0);
            accs[t] = __builtin_amdgcn_mfma_f32_16x16x32_bf16(A0, Bs[t][0], z4, 0, 0, 0);
        }
        #pragma unroll
        for (int t = 0; t < 4; ++t) {
            accf[t] = __builtin_amdgcn_mfma_f32_16x16x32_bf16(A1, Bf[t][1], accf[t], 0, 0, 0);
            accs[t] = __builtin_amdgcn_mfma_f32_16x16x32_bf16(A1, Bs[t][1], accs[t], 0, 0, 0);
        }
        #pragma unroll
        for (int r = 0; r < 4; ++r) {
            long node = base + g * 4 + r;
            f32x4 vf = {accf[0][r] + bfv[0], accf[1][r] + bfv[1],
                        accf[2][r] + bfv[2], accf[3][r] + bfv[3]};
            f32x4 vs = {accs[0][r] + bsv[0], accs[1][r] + bsv[1],
                        accs[2][r] + bsv[2], accs[3][r] + bsv[3]};
            *(f32x4*)(Ttgt + node * 128 + cc * 4) = vf;
            *(f32x4*)(Ttgt + node * 128 + 64 + cc * 4) = vs;
        }
    }
}

// ---------------------------------------------------------------------------
// Edge kernel: one wave per target, chunk-ahead pipeline, B in LDS.
// launch_bounds(256,3): ~170 VGPR budget -> no spill (the (256,4) attempt
// spilled the fragment set: 2.5 GB scratch traffic, 5x regression).
// 3 waves/SIMD vs round-6's 2 -> 1.5x TLP with the same instruction stream.
// ---------------------------------------------------------------------------
#define BL(t, ck) (*(const short8*)(Bl + (((t) * 4 + (ck)) * 512 + lane * 8)))

__global__ __launch_bounds__(256, 3) void edge_kernel(
    const ushort* __restrict__ eab_s, const int* __restrict__ srcs,
    const int* __restrict__ rowptr, const ushort* __restrict__ h_bf,
    const float* __restrict__ h, const float* __restrict__ Ttgt,
    const ushort* __restrict__ Bpack, float* __restrict__ agg,
    float* __restrict__ stats) {
    __shared__ ushort Bl[16384];          // 32 KB: same layout as Bpack
    __shared__ float ls[4][64], lq[4][64];
    for (int i = threadIdx.x; i < 2048; i += 256)
        ((uint4*)Bl)[i] = ((const uint4*)Bpack)[i];
    __syncthreads();

    int lane = threadIdx.x & 63;
    int q = lane >> 4;
    int c = lane & 15;
    int wid = (blockIdx.x * blockDim.x + threadIdx.x) >> 6;
    int nw = (gridDim.x * blockDim.x) >> 6;
    const short8 z8 = {0, 0, 0, 0, 0, 0, 0, 0};

    float st1 = 0.f, st2 = 0.f;
    int tn = wid;
    int r0 = 0, r1 = 0, svAll = 0;
    short8 A0, A1, A2, A3;
    if (tn < NNODES) {
        r0 = rowptr[tn]; r1 = rowptr[tn + 1];
        int e = r0 + lane; if (e > NEDGES - 1) e = NEDGES - 1;
        svAll = srcs[e];
        int sv = __shfl(svAll, c, 64);
        int ei = r0 + c; if (ei > NEDGES - 1) ei = NEDGES - 1;
        const short8* hrow = (const short8*)(h_bf + (long)sv * 64);
        const ushort* erow = eab_s + (long)ei * ECOLS;
        A0 = hrow[q]; A1 = hrow[4 + q];
        A2 = *(const short8*)(erow + q * 8);
        A3 = z8;
        if (q < 2) A3 = *(const short8*)(erow + 32 + q * 8);
    }

    while (tn < NNODES) {
        int tn2 = tn + nw;
        int r0n = 0, r1n = 0;
        if (tn2 < NNODES) { r0n = rowptr[tn2]; r1n = rowptr[tn2 + 1]; }
        f32x4 tf = *(const f32x4*)(Ttgt + (long)tn * 128 + 4 * c);
        f32x4 ts = *(const f32x4*)(Ttgt + (long)tn * 128 + 64 + 4 * c);
        int d = r1 - r0;
        int nch = (d + 15) >> 4;
        float vs0 = 0.f, vs1 = 0.f, vs2 = 0.f, vs3 = 0.f;

        if (nch == 0) {
            // isolated node: still prefetch next target's chunk 0
            int e = r0n + lane; if (e > NEDGES - 1) e = NEDGES - 1;
            svAll = srcs[e];
            int sv = __shfl(svAll, c, 64);
            int ei = r0n + c; if (ei > NEDGES - 1) ei = NEDGES - 1;
            const short8* hrow = (const short8*)(h_bf + (long)sv * 64);
            const ushort* erow = eab_s + (long)ei * ECOLS;
            A0 = hrow[q]; A1 = hrow[4 + q];
            A2 = *(const short8*)(erow + q * 8);
            A3 = z8;
            if (q < 2) A3 = *(const short8*)(erow + 32 + q * 8);
        } else {
            for (int ci = 0; ci < nch; ++ci) {
                // ---- issue prefetch for chunk ci+1 (or next target's chunk 0)
                int sv, ei;
                int nidx = ci + 1;
                if (nidx < nch) {
                    if ((nidx & 3) == 0) {       // superchunk boundary (d>64, rare)
                        int e = r0 + nidx * 16 + lane;
                        if (e > NEDGES - 1) e = NEDGES - 1;
                        svAll = srcs[e];
                    }
                    sv = __shfl(svAll, ((nidx & 3) << 4) + c, 64);
                    ei = r0 + nidx * 16 + c;
                    if (ei > NEDGES - 1) ei = NEDGES - 1;
                } else {
                    int e = r0n + lane; if (e > NEDGES - 1) e = NEDGES - 1;
                    svAll = srcs[e];
                    sv = __shfl(svAll, c, 64);
                    ei = r0n + c; if (ei > NEDGES - 1) ei = NEDGES - 1;
                }
                const short8* hrow = (const short8*)(h_bf + (long)sv * 64);
                const ushort* erow = eab_s + (long)ei * ECOLS;
                short8 N0 = hrow[q], N1 = hrow[4 + q];
                short8 N2 = *(const short8*)(erow + q * 8);
                short8 N3 = z8;
                if (q < 2) N3 = *(const short8*)(erow + 32 + q * 8);

                // ---- compute current chunk (A resident; B from LDS) ----
                f32x4 accf[4], accs[4];
                f32x4 z4 = {0.f, 0.f, 0.f, 0.f};
                __builtin_amdgcn_s_setprio(1);
                #pragma unroll
                for (int t = 0; t < 4; ++t) {
                    accf[t] = __builtin_amdgcn_mfma_f32_16x16x32_bf16(A0, BL(t, 0), z4, 0, 0, 0);
                    accs[t] = __builtin_amdgcn_mfma_f32_16x16x32_bf16(A0, BL(t + 4, 0), z4, 0, 0, 0);
                }
                #pragma unroll
                for (int t = 0; t < 4; ++t) {
                    accf[t] = __builtin_amdgcn_mfma_f32_16x16x32_bf16(A1, BL(t, 1), accf[t], 0, 0, 0);
                    accs[t] = __builtin_amdgcn_mfma_f32_16x16x32_bf16(A1, BL(t + 4, 1), accs[t], 0, 0, 0);
                }
                #pragma unroll
                for (int t = 0; t < 4; ++t) {
                    accf[t] = __builtin_amdgcn_mfma_f32_16x16x32_bf16(A2, BL(t, 2), accf[t], 0, 0, 0);
                    accs[t] = __builtin_amdgcn_mfma_f32_16x16x32_bf16(A2, BL(t + 4, 2), accs[t], 0, 0, 0);
                }
                #pragma unroll
                for (int t = 0; t < 4; ++t) {
                    accf[t] = __builtin_amdgcn_mfma_f32_16x16x32_bf16(A3, BL(t, 3), accf[t], 0, 0, 0);
                    accs[t] = __builtin_amdgcn_mfma_f32_16x16x32_bf16(A3, BL(t + 4, 3), accs[t], 0, 0, 0);
                }
                __builtin_amdgcn_s_setprio(0);

                int base = ci * 16 + q * 4;
                #pragma unroll
                for (int r = 0; r < 4; ++r) {
                    bool valid = (base + r) < d;
                    #pragma unroll
                    for (int t = 0; t < 4; ++t) {
                        float f = accf[t][r] + tf[t];
                        float s = accs[t][r] + ts[t];
                        float g = __builtin_amdgcn_rcpf(1.f + __expf(-f));
                        float sp = fmaxf(s, 0.f) + __logf(1.f + __expf(-fabsf(s)));
                        float msg = valid ? g * sp : 0.f;
                        if (t == 0) vs0 += msg;
                        else if (t == 1) vs1 += msg;
                        else if (t == 2) vs2 += msg;
                        else vs3 += msg;
                    }
                }
                A0 = N0; A1 = N1; A2 = N2; A3 = N3;
            }
        }
        vs0 += __shfl_xor(vs0, 16, 64); vs0 += __shfl_xor(vs0, 32, 64);
        vs1 += __shfl_xor(vs1, 16, 64); vs1 += __shfl_xor(vs1, 32, 64);
        vs2 += __shfl_xor(vs2, 16, 64); vs2 += __shfl_xor(vs2, 32, 64);
        vs3 += __shfl_xor(vs3, 16, 64); vs3 += __shfl_xor(vs3, 32, 64);
        float out = (q == 0) ? vs0 : (q == 1) ? vs1 : (q == 2) ? vs2 : vs3;
        agg[(long)tn * 64 + lane] = out;           // channel = q*16+c = lane
        float v = h[(long)tn * 64 + lane] + out;
        st1 += v;
        st2 = fmaf(v, v, st2);

        tn = tn2; r0 = r0n; r1 = r1n;
    }

    // block-level stats reduction -> 2 atomics/lane/block
    int w = threadIdx.x >> 6;
    ls[w][lane] = st1; lq[w][lane] = st2;
    __syncthreads();
    if (threadIdx.x < 64) {
        float t1 = ls[0][lane] + ls[1][lane] + ls[2][lane] + ls[3][lane];
        float t2 = lq[0][lane] + lq[1][lane] + lq[2][lane] + lq[3][lane];
        atomicAdd(&stats[lane], t1);
        atomicAdd(&stats[64 + lane], t2);
    }
}

// ---------------------------------------------------------------------------
// bnproj: BN apply (+ReLU) fused with NEXT layer's target projection.
// ---------------------------------------------------------------------------
__global__ __launch_bounds__(256) void bnproj(
    float* __restrict__ h, const float* __restrict__ agg,
    const float* __restrict__ stats, const float* __restrict__ gamma,
    const float* __restrict__ beta, ushort* __restrict__ h_bf,
    const ushort* __restrict__ Tpack_l, const float* __restrict__ bcf_l,
    const float* __restrict__ bcs_l, float* __restrict__ Ttgt) {
    int lane = threadIdx.x & 63;
    int cc = lane & 15;
    int g = lane >> 4;
    short8 Bf[4][2], Bs[4][2];
    #pragma unroll
    for (int t = 0; t < 4; ++t)
        #pragma unroll
        for (int ck = 0; ck < 2; ++ck) {
            Bf[t][ck] = *(const short8*)(Tpack_l + (t * 2 + ck) * 512 + lane * 8);
            Bs[t][ck] = *(const short8*)(Tpack_l + 4096 + (t * 2 + ck) * 512 + lane * 8);
        }
    float bfv[4], bsv[4];
    #pragma unroll
    for (int t = 0; t < 4; ++t) {
        bfv[t] = bcf_l[t * 16 + cc];
        bsv[t] = bcs_l[t * 16 + cc];
    }
    const float invn = 1.f / (float)NNODES;
    float sc[16], sh[16];
    #pragma unroll
    for (int m = 0; m < 16; ++m) {
        int ch = (m < 8) ? (g * 8 + m) : (32 + g * 8 + (m - 8));
        float mu = stats[ch] * invn;
        float va = stats[64 + ch] * invn - mu * mu;
        float s = rsqrtf(va + BN_EPS) * gamma[ch];
        sc[m] = s;
        sh[m] = beta[ch] - mu * s;
    }
    int wid = (blockIdx.x * blockDim.x + threadIdx.x) >> 6;
    int nw = (gridDim.x * blockDim.x) >> 6;
    for (int nb = wid; nb < NNODES / 16; nb += nw) {
        long base = (long)nb * 16;
        long row = base + cc;
        float* hr = h + row * 64;
        const float* ar = agg + row * 64;
        float y[16];
        #pragma unroll
        for (int half = 0; half < 2; ++half) {
            int col = half * 32 + g * 8;
            f32x4 hv0 = *(const f32x4*)(hr + col);
            f32x4 hv1 = *(const f32x4*)(hr + col + 4);
            f32x4 av0 = *(const f32x4*)(ar + col);
            f32x4 av1 = *(const f32x4*)(ar + col + 4);
            #pragma unroll
            for (int m = 0; m < 4; ++m) {
                float t0 = (hv0[m] + av0[m]) * sc[half * 8 + m] + sh[half * 8 + m];
                float t1 = (hv1[m] + av1[m]) * sc[half * 8 + 4 + m] + sh[half * 8 + 4 + m];
                y[half * 8 + m] = fmaxf(t0, 0.f);        // relu (layers 0,1 only)
                y[half * 8 + 4 + m] = fmaxf(t1, 0.f);
            }
        }
        f32x4 w0 = {y[0], y[1], y[2], y[3]},   w1 = {y[4], y[5], y[6], y[7]};
        f32x4 w2 = {y[8], y[9], y[10], y[11]}, w3 = {y[12], y[13], y[14], y[15]};
        *(f32x4*)(hr + g * 8) = w0;       *(f32x4*)(hr + g * 8 + 4) = w1;
        *(f32x4*)(hr + 32 + g * 8) = w2;  *(f32x4*)(hr + 32 + g * 8 + 4) = w3;
        uint u[8];
        #pragma unroll
        for (int m = 0; m < 8; ++m)
            u[m] = (uint)f2bf(y[m * 2]) | ((uint)f2bf(y[m * 2 + 1]) << 16);
        uint4 p0; p0.x = u[0]; p0.y = u[1]; p0.z = u[2]; p0.w = u[3];
        uint4 p1; p1.x = u[4]; p1.y = u[5]; p1.z = u[6]; p1.w = u[7];
        *(uint4*)(h_bf + row * 64 + g * 8) = p0;
        *(uint4*)(h_bf + row * 64 + 32 + g * 8) = p1;
        short8 A0 = *reinterpret_cast<short8*>(&p0);
        short8 A1 = *reinterpret_cast<short8*>(&p1);

        f32x4 accf[4], accs[4];
        f32x4 z4 = {0.f, 0.f, 0.f, 0.f};
        #pragma unroll
        for (int t = 0; t < 4; ++t) {
            accf[t] = __builtin_amdgcn_mfma_f32_16x16x32_bf16(A0, Bf[t][0], z4, 0, 0, 0);
            accs[t] = __builtin_amdgcn_mfma_f32_16x16x32_bf16(A0, Bs[t][0], z4, 0, 0, 0);
        }
        #pragma unroll
        for (int t = 0; t < 4; ++t) {
            accf[t] = __builtin_amdgcn_mfma_f32_16x16x32_bf16(A1, Bf[t][1], accf[t], 0, 0, 0);
            accs[t] = __builtin_amdgcn_mfma_f32_16x16x32_bf16(A1, Bs[t][1], accs[t], 0, 0, 0);
        }
        #pragma unroll
        for (int r = 0; r < 4; ++r) {
            long node = base + g * 4 + r;
            f32x4 vf = {accf[0][r] + bfv[0], accf[1][r] + bfv[1],
                        accf[2][r] + bfv[2], accf[3][r] + bfv[3]};
            f32x4 vs = {accs[0][r] + bsv[0], accs[1][r] + bsv[1],
                        accs[2][r] + bsv[2], accs[3][r] + bsv[3]};
            *(f32x4*)(Ttgt + node * 128 + cc * 4) = vf;
            *(f32x4*)(Ttgt + node * 128 + 64 + cc * 4) = vs;
        }
    }
}

// ---------------------------------------------------------------------------
// bn_final: last layer BN (no relu, no h_bf, no proj). Pure streaming.
// ---------------------------------------------------------------------------
__global__ __launch_bounds__(256) void bn_final(
    float* __restrict__ h, const float* __restrict__ agg,
    const float* __restrict__ stats, const float* __restrict__ gamma,
    const float* __restrict__ beta) {
    int tid = blockIdx.x * blockDim.x + threadIdx.x;
    int nth = gridDim.x * blockDim.x;   // multiple of 16
    const float invn = 1.f / (float)NNODES;
    int cb = (tid & 15) * 4;
    f32x4 sc, sh;
    #pragma unroll
    for (int j = 0; j < 4; ++j) {
        float m = stats[cb + j] * invn;
        float v = stats[64 + cb + j] * invn - m * m;
        float s = rsqrtf(v + BN_EPS) * gamma[cb + j];
        sc[j] = s;
        sh[j] = beta[cb + j] - m * s;
    }
    for (long i = tid; i < (long)NNODES * 16; i += nth) {
        f32x4 v = ((const f32x4*)h)[i];
        f32x4 a = ((const f32x4*)agg)[i];
        f32x4 y;
        #pragma unroll
        for (int j = 0; j < 4; ++j) y[j] = (v[j] + a[j]) * sc[j] + sh[j];
        ((f32x4*)h)[i] = y;
    }
}

extern "C" void kernel_launch(void* const* d_in, const int* in_sizes, int n_in,
                              void* d_out, int out_size, void* d_ws, size_t ws_size,
                              hipStream_t stream) {
    const float* x    = (const float*)d_in[0];
    const float* ea   = (const float*)d_in[1];
    const int*   eidx = (const int*)d_in[2];
    const float* W1   = (const float*)d_in[3];
    const float* b1   = (const float*)d_in[4];
    const float* W2   = (const float*)d_in[5];
    const float* b2   = (const float*)d_in[6];
    const float* Wf   = (const float*)d_in[7];
    const float* bf   = (const float*)d_in[8];
    const float* Ws   = (const float*)d_in[9];
    const float* bs   = (const float*)d_in[10];
    const float* gamma= (const float*)d_in[11];
    const float* beta = (const float*)d_in[12];
    float* h = (float*)d_out; // [NNODES, 64]

    // workspace layout (256 B aligned sections)
    char* wb = (char*)d_ws;
    auto align = [&]() { wb = (char*)(((size_t)wb + 255) & ~(size_t)255); };
    ushort* Bpack = (ushort*)wb;  wb += 3 * 8 * 4 * 512 * sizeof(ushort); align(); // 96 KB
    ushort* Tpack = (ushort*)wb;  wb += 3 * 2 * 4 * 2 * 512 * sizeof(ushort); align(); // 48 KB
    float* bcf   = (float*)wb;    wb += 3 * HID * sizeof(float);
    float* bcs   = (float*)wb;    wb += 3 * HID * sizeof(float);
    float* stats = (float*)wb;    wb += 3 * 2 * HID * sizeof(float); align();
    int* deg     = (int*)wb;      wb += NNODES * sizeof(int);
    int* rowptr  = (int*)wb;      wb += (NNODES + 1) * sizeof(int);
    int* cursor  = (int*)wb;      wb += NNODES * sizeof(int);
    int* bsum    = (int*)wb;      wb += 256 * sizeof(int);
    int* bbase   = (int*)wb;      wb += 256 * sizeof(int); align();
    int* srcs    = (int*)wb;      wb += NEDGES * sizeof(int);          // 3.2 MB
    align();
    float* Ttgt  = (float*)wb;    wb += (size_t)NNODES * 128 * sizeof(float); // 25.6 MB
    float* agg   = (float*)wb;    wb += (size_t)NNODES * HID * sizeof(float); // 12.8 MB
    ushort* h_bf = (ushort*)wb;   wb += (size_t)NNODES * HID * sizeof(ushort); // 6.4 MB
    ushort* eab_s= (ushort*)wb;   wb += (size_t)NEDGES * ECOLS * sizeof(ushort); // 76.8 MB

    // --- setup ---
    hipMemsetAsync(deg, 0, NNODES * sizeof(int), stream);
    prep_embed<<<EMBED_BASE + EMBED_BLOCKS, 256, 0, stream>>>(
        W2, b2, Wf, bf, Ws, bs, Bpack, Tpack, bcf, bcs, stats, deg, eidx,
        x, W1, b1, h, h_bf);
    k_blocksum<<<196, 256, 0, stream>>>(deg, bsum);
    k_scanbase<<<1, 256, 0, stream>>>(bsum, bbase, rowptr);
    k_writerow<<<196, 256, 0, stream>>>(deg, bbase, rowptr, cursor);
    scat_proj<<<SCAT_BLOCKS + PROJ_BLOCKS, 256, 0, stream>>>(
        eidx, cursor, srcs, ea, eab_s, h_bf, Tpack, bcf, bcs, Ttgt);

    for (int i = 0; i < 3; ++i) {
        edge_kernel<<<2048, 256, 0, stream>>>(eab_s, srcs, rowptr, h_bf, h, Ttgt,
                                              Bpack + i * 16384, agg, stats + i * 128);
        if (i < 2)
            bnproj<<<1024, 256, 0, stream>>>(h, agg, stats + i * 128, gamma + i * HID,
                                             beta + i * HID, h_bf,
                                             Tpack + (i + 1) * 8192,
                                             bcf + (i + 1) * HID, bcs + (i + 1) * HID,
                                             Ttgt);
        else
            bn_final<<<2048, 256, 0, stream>>>(h, agg, stats + i * 128,
                                               gamma + i * HID, beta + i * HID);
    }
}

// Round 9
// 763.997 us; speedup vs baseline: 2.7697x; 1.9839x over previous
//
#include <hip/hip_runtime.h>
#include <cmath>

#define NNODES 50000
#define NEDGES 800000
#define ORIG_FEA 92
#define NBR_FEA 41
#define HID 64
#define BN_EPS 1e-5f
#define ECOLS 48          // eab_s columns: 41 real + 7 pad

typedef __attribute__((ext_vector_type(8))) short short8;
typedef __attribute__((ext_vector_type(4))) float f32x4;
typedef unsigned short ushort;
typedef unsigned int uint;

static __device__ __forceinline__ ushort f2bf(float f) {
    uint u = __float_as_uint(f);
    uint r = u + 0x7fffu + ((u >> 16) & 1u);   // round-to-nearest-even
    return (ushort)(r >> 16);
}

// ---------------------------------------------------------------------------
// prep_embed: all input-only setup in ONE launch (deg zeroed by memset first).
//  blocks 0..23      : Bpack/Tpack/bias packing (6 groups x 4 quarters)
//  block  24         : zero BN stats
//  blocks 25..3149   : k_hist (800K edges, atomics on deg)
//  blocks 3150..4173 : embed h = x @ W1 + b1 (coalesced x load + shfl bcast)
// ---------------------------------------------------------------------------
#define HIST_BASE 25
#define HIST_BLOCKS 3125
#define EMBED_BASE (HIST_BASE + HIST_BLOCKS)   // 3150
#define EMBED_BLOCKS 1024

__global__ __launch_bounds__(256) void prep_embed(
    const float* __restrict__ W2, const float* __restrict__ b2,
    const float* __restrict__ Wf, const float* __restrict__ bf,
    const float* __restrict__ Ws, const float* __restrict__ bs,
    ushort* __restrict__ Bpack, ushort* __restrict__ Tpack,
    float* __restrict__ bcf, float* __restrict__ bcs,
    float* __restrict__ stats, int* __restrict__ deg,
    const int* __restrict__ eidx,
    const float* __restrict__ x, const float* __restrict__ W1,
    const float* __restrict__ b1, float* __restrict__ h,
    ushort* __restrict__ h_bf) {
    if (blockIdx.x >= EMBED_BASE) {
        int lane = threadIdx.x & 63;
        int wid = (((int)blockIdx.x - EMBED_BASE) * 256 + (int)threadIdx.x) >> 6;
        int nw = (EMBED_BLOCKS * 256) >> 6;
        float b1v = b1[lane];
        for (int n = wid; n < NNODES; n += nw) {
            const float* xr = x + (long)n * ORIG_FEA;
            float xa = xr[lane];
            float xb = (lane < ORIG_FEA - 64) ? xr[64 + lane] : 0.f;
            float a0 = b1v, a1 = 0.f, a2 = 0.f, a3 = 0.f;
            #pragma unroll
            for (int k = 0; k < 64; k += 4) {
                a0 = fmaf(__shfl(xa, k, 64),     W1[k * HID + lane], a0);
                a1 = fmaf(__shfl(xa, k + 1, 64), W1[(k + 1) * HID + lane], a1);
                a2 = fmaf(__shfl(xa, k + 2, 64), W1[(k + 2) * HID + lane], a2);
                a3 = fmaf(__shfl(xa, k + 3, 64), W1[(k + 3) * HID + lane], a3);
            }
            #pragma unroll
            for (int k = 0; k < ORIG_FEA - 64; k += 4) {
                a0 = fmaf(__shfl(xb, k, 64),     W1[(64 + k) * HID + lane], a0);
                a1 = fmaf(__shfl(xb, k + 1, 64), W1[(65 + k) * HID + lane], a1);
                a2 = fmaf(__shfl(xb, k + 2, 64), W1[(66 + k) * HID + lane], a2);
                a3 = fmaf(__shfl(xb, k + 3, 64), W1[(67 + k) * HID + lane], a3);
            }
            float acc = (a0 + a1) + (a2 + a3);
            h[(long)n * HID + lane] = acc;
            h_bf[(long)n * HID + lane] = f2bf(acc);
        }
        return;
    }
    if (blockIdx.x >= HIST_BASE) {
        int e = ((int)blockIdx.x - HIST_BASE) * 256 + (int)threadIdx.x;
        if (e < NEDGES) atomicAdd(&deg[eidx[NEDGES + e]], 1);
        return;
    }
    if (blockIdx.x == 24) {
        for (int i = threadIdx.x; i < 3 * 128; i += blockDim.x) stats[i] = 0.f;
        return;
    }
    // blocks 0..23: weight packing
    int group = blockIdx.x >> 2;       // 0..5 = (layer, fs)
    int quarter = blockIdx.x & 3;
    int layer = group >> 1;
    int fs = group & 1;
    const float* Wbig = (fs ? Ws : Wf) + layer * 192 * HID;
    const float* We = Wbig + 128 * HID;                 // e-part rows
    const float* bvec = (fs ? bs : bf) + layer * HID;
    float* bc = (fs ? bcs : bcf) + layer * HID;
    ushort* Bp = Bpack + layer * 16384 + fs * 8192;     // t = fs*4 + tt
    ushort* Tp = Tpack + layer * 8192 + fs * 4096;

    for (int idx = quarter * 2048 + threadIdx.x; idx < (quarter + 1) * 2048;
         idx += blockDim.x) {
        int j = idx & 7;
        int lane = (idx >> 3) & 63;
        int ck = (idx >> 9) & 3;
        int tt = (idx >> 11) & 3;
        int k = ck * 32 + ((lane >> 4) * 8) + j;
        int col = tt * 16 + (lane & 15);
        float v = 0.f;
        if (k < 64) v = Wbig[(64 + k) * HID + col];
        else if (k < 64 + NBR_FEA) {
            int r = k - 64;
            float a = 0.f;
            for (int m = 0; m < HID; ++m) a += W2[r * HID + m] * We[m * HID + col];
            v = a;
        }
        Bp[(tt * 4 + ck) * 512 + lane * 8 + j] = f2bf(v);
    }
    // target-block B fragments (K=64), quarter-split
    for (int idx = quarter * 1024 + threadIdx.x; idx < (quarter + 1) * 1024;
         idx += blockDim.x) {
        int j = idx & 7;
        int lane = (idx >> 3) & 63;
        int ck = (idx >> 9) & 1;
        int t = (idx >> 10) & 3;
        int k = ck * 32 + ((lane >> 4) * 8) + j;
        int col = t * 16 + (lane & 15);
        Tp[(t * 2 + ck) * 512 + lane * 8 + j] = f2bf(Wbig[k * HID + col]);
    }
    if (quarter == 3) {
        for (int c0 = threadIdx.x; c0 < HID; c0 += blockDim.x) {
            float a = bvec[c0];
            for (int m = 0; m < HID; ++m) a += b2[m] * We[m * HID + c0];
            bc[c0] = a;
        }
    }
}

// ---------------------------------------------------------------------------
// CSR scan kernels
// ---------------------------------------------------------------------------
__global__ void k_blocksum(const int* __restrict__ deg, int* __restrict__ bsum) {
    __shared__ int sh[256];
    int i = blockIdx.x * 256 + threadIdx.x;
    sh[threadIdx.x] = (i < NNODES) ? deg[i] : 0;
    __syncthreads();
    for (int s = 128; s > 0; s >>= 1) {
        if (threadIdx.x < s) sh[threadIdx.x] += sh[threadIdx.x + s];
        __syncthreads();
    }
    if (threadIdx.x == 0) bsum[blockIdx.x] = sh[0];
}

__global__ void k_scanbase(const int* __restrict__ bsum, int* __restrict__ bbase,
                           int* __restrict__ rowptr) {
    __shared__ int sh[256];
    int t = threadIdx.x;
    int v = (t < 196) ? bsum[t] : 0;
    sh[t] = v;
    __syncthreads();
    for (int s = 1; s < 256; s <<= 1) {
        int add = (t >= s) ? sh[t - s] : 0;
        __syncthreads();
        sh[t] += add;
        __syncthreads();
    }
    if (t < 196) bbase[t] = sh[t] - v;   // exclusive
    if (t == 0) rowptr[NNODES] = NEDGES;
}

__global__ void k_writerow(const int* __restrict__ deg, const int* __restrict__ bbase,
                           int* __restrict__ rowptr, int* __restrict__ cursor) {
    __shared__ int sh[256];
    int t = threadIdx.x;
    int i = blockIdx.x * 256 + t;
    int v = (i < NNODES) ? deg[i] : 0;
    sh[t] = v;
    __syncthreads();
    for (int s = 1; s < 256; s <<= 1) {
        int add = (t >= s) ? sh[t - s] : 0;
        __syncthreads();
        sh[t] += add;
        __syncthreads();
    }
    if (i < NNODES) {
        int e = bbase[blockIdx.x] + sh[t] - v;
        rowptr[i] = e;
        cursor[i] = e;
    }
}

// ---------------------------------------------------------------------------
// scat_proj: one launch, two independent jobs.
//  blocks < 3125 : CSR scatter + eab row build (thread-per-edge; 41 ea loads
//                  issued before the atomic; 96 B row write to slot pos)
//  blocks >= 3125: layer-0 proj_mfma (Ttgt = h_bf @ W_tgt + bc)
// ---------------------------------------------------------------------------
#define SCAT_BLOCKS 3125
#define PROJ_BLOCKS 1024

__global__ __launch_bounds__(256) void scat_proj(
    const int* __restrict__ eidx, int* __restrict__ cursor,
    int* __restrict__ srcs, const float* __restrict__ ea,
    ushort* __restrict__ eab_s,
    const ushort* __restrict__ h_bf, const ushort* __restrict__ Tpack_l,
    const float* __restrict__ bcf_l, const float* __restrict__ bcs_l,
    float* __restrict__ Ttgt) {
    if (blockIdx.x < SCAT_BLOCKS) {
        int e = blockIdx.x * 256 + threadIdx.x;
        if (e >= NEDGES) return;
        const float* row = ea + (long)e * NBR_FEA;
        float a[NBR_FEA];
        #pragma unroll
        for (int k = 0; k < NBR_FEA; ++k) a[k] = row[k];
        int tgt = eidx[NEDGES + e];
        int pos = atomicAdd(&cursor[tgt], 1);
        srcs[pos] = eidx[e];
        uint u[24];
        #pragma unroll
        for (int m = 0; m < 20; ++m)
            u[m] = (uint)f2bf(a[2 * m]) | ((uint)f2bf(a[2 * m + 1]) << 16);
        u[20] = (uint)f2bf(a[40]);
        u[21] = 0u; u[22] = 0u; u[23] = 0u;
        uint4* dst = (uint4*)(eab_s + (long)pos * ECOLS);
        #pragma unroll
        for (int m = 0; m < 6; ++m) {
            uint4 o; o.x = u[4 * m]; o.y = u[4 * m + 1];
            o.z = u[4 * m + 2]; o.w = u[4 * m + 3];
            dst[m] = o;
        }
        return;
    }
    // ---- proj branch ----
    int lane = threadIdx.x & 63;
    int cc = lane & 15;
    int g = lane >> 4;
    short8 Bf[4][2], Bs[4][2];
    #pragma unroll
    for (int t = 0; t < 4; ++t)
        #pragma unroll
        for (int ck = 0; ck < 2; ++ck) {
            Bf[t][ck] = *(const short8*)(Tpack_l + (t * 2 + ck) * 512 + lane * 8);
            Bs[t][ck] = *(const short8*)(Tpack_l + 4096 + (t * 2 + ck) * 512 + lane * 8);
        }
    float bfv[4], bsv[4];
    #pragma unroll
    for (int t = 0; t < 4; ++t) {
        bfv[t] = bcf_l[t * 16 + cc];
        bsv[t] = bcs_l[t * 16 + cc];
    }
    int wid = (((int)blockIdx.x - SCAT_BLOCKS) * 256 + (int)threadIdx.x) >> 6;
    int nw = (PROJ_BLOCKS * 256) >> 6;
    for (int nb = wid; nb < NNODES / 16; nb += nw) {
        long base = (long)nb * 16;
        long row = base + cc;
        short8 A0 = *(const short8*)(h_bf + row * 64 + g * 8);
        short8 A1 = *(const short8*)(h_bf + row * 64 + 32 + g * 8);
        f32x4 accf[4], accs[4];
        f32x4 z4 = {0.f, 0.f, 0.f, 0.f};
        #pragma unroll
        for (int t = 0; t < 4; ++t) {
            accf[t] = __builtin_amdgcn_mfma_f32_16x16x32_bf16(A0, Bf[t][0], z4, 0, 0, 0);
            accs[t] = __builtin_amdgcn_mfma_f32_16x16x32_bf16(A0, Bs[t][0], z4, 0, 0, 0);
        }
        #pragma unroll
        for (int t = 0; t < 4; ++t) {
            accf[t] = __builtin_amdgcn_mfma_f32_16x16x32_bf16(A1, Bf[t][1], accf[t], 0, 0, 0);
            accs[t] = __builtin_amdgcn_mfma_f32_16x16x32_bf16(A1, Bs[t][1], accs[t], 0, 0, 0);
        }
        #pragma unroll
        for (int r = 0; r < 4; ++r) {
            long node = base + g * 4 + r;
            f32x4 vf = {accf[0][r] + bfv[0], accf[1][r] + bfv[1],
                        accf[2][r] + bfv[2], accf[3][r] + bfv[3]};
            f32x4 vs = {accs[0][r] + bsv[0], accs[1][r] + bsv[1],
                        accs[2][r] + bsv[2], accs[3][r] + bsv[3]};
            *(f32x4*)(Ttgt + node * 128 + cc * 4) = vf;
            *(f32x4*)(Ttgt + node * 128 + 64 + cc * 4) = vs;
        }
    }
}

// ---------------------------------------------------------------------------
// Edge kernel: one wave per target, chunk-ahead pipeline, B register-resident
// (round-6 version, measured 127 us / 107 MB FETCH / no scratch).
// The LDS-B experiments (rounds 7/8) spilled: LICM hoists the loop-invariant
// ds_reads back into registers, recreating the 128-reg B array on top of the
// live state -> scratch. Register-B at 2 waves/SIMD is the proven optimum
// for this structure.
// ---------------------------------------------------------------------------
__global__ __launch_bounds__(256, 2) void edge_kernel(
    const ushort* __restrict__ eab_s, const int* __restrict__ srcs,
    const int* __restrict__ rowptr, const ushort* __restrict__ h_bf,
    const float* __restrict__ h, const float* __restrict__ Ttgt,
    const ushort* __restrict__ Bpack, float* __restrict__ agg,
    float* __restrict__ stats) {
    int lane = threadIdx.x & 63;
    int q = lane >> 4;
    int c = lane & 15;
    int wid = (blockIdx.x * blockDim.x + threadIdx.x) >> 6;
    int nw = (gridDim.x * blockDim.x) >> 6;
    const short8 z8 = {0, 0, 0, 0, 0, 0, 0, 0};

    short8 B[8][4];
    #pragma unroll
    for (int t = 0; t < 8; ++t)
        #pragma unroll
        for (int ck = 0; ck < 4; ++ck)
            B[t][ck] = *(const short8*)(Bpack + ((t * 4 + ck) * 512 + lane * 8));

    float st1 = 0.f, st2 = 0.f;
    int tn = wid;
    int r0 = 0, r1 = 0, svAll = 0;
    short8 A0, A1, A2, A3;
    if (tn < NNODES) {
        r0 = rowptr[tn]; r1 = rowptr[tn + 1];
        int e = r0 + lane; if (e > NEDGES - 1) e = NEDGES - 1;
        svAll = srcs[e];
        int sv = __shfl(svAll, c, 64);
        int ei = r0 + c; if (ei > NEDGES - 1) ei = NEDGES - 1;
        const short8* hrow = (const short8*)(h_bf + (long)sv * 64);
        const ushort* erow = eab_s + (long)ei * ECOLS;
        A0 = hrow[q]; A1 = hrow[4 + q];
        A2 = *(const short8*)(erow + q * 8);
        A3 = z8;
        if (q < 2) A3 = *(const short8*)(erow + 32 + q * 8);
    }

    while (tn < NNODES) {
        int tn2 = tn + nw;
        int r0n = 0, r1n = 0;
        if (tn2 < NNODES) { r0n = rowptr[tn2]; r1n = rowptr[tn2 + 1]; }
        f32x4 tf = *(const f32x4*)(Ttgt + (long)tn * 128 + 4 * c);
        f32x4 ts = *(const f32x4*)(Ttgt + (long)tn * 128 + 64 + 4 * c);
        int d = r1 - r0;
        int nch = (d + 15) >> 4;
        float vs0 = 0.f, vs1 = 0.f, vs2 = 0.f, vs3 = 0.f;

        if (nch == 0) {
            // isolated node: still prefetch next target's chunk 0
            int e = r0n + lane; if (e > NEDGES - 1) e = NEDGES - 1;
            svAll = srcs[e];
            int sv = __shfl(svAll, c, 64);
            int ei = r0n + c; if (ei > NEDGES - 1) ei = NEDGES - 1;
            const short8* hrow = (const short8*)(h_bf + (long)sv * 64);
            const ushort* erow = eab_s + (long)ei * ECOLS;
            A0 = hrow[q]; A1 = hrow[4 + q];
            A2 = *(const short8*)(erow + q * 8);
            A3 = z8;
            if (q < 2) A3 = *(const short8*)(erow + 32 + q * 8);
        } else {
            for (int ci = 0; ci < nch; ++ci) {
                // ---- issue prefetch for chunk ci+1 (or next target's chunk 0)
                int sv, ei;
                int nidx = ci + 1;
                if (nidx < nch) {
                    if ((nidx & 3) == 0) {       // superchunk boundary (d>64, rare)
                        int e = r0 + nidx * 16 + lane;
                        if (e > NEDGES - 1) e = NEDGES - 1;
                        svAll = srcs[e];
                    }
                    sv = __shfl(svAll, ((nidx & 3) << 4) + c, 64);
                    ei = r0 + nidx * 16 + c;
                    if (ei > NEDGES - 1) ei = NEDGES - 1;
                } else {
                    int e = r0n + lane; if (e > NEDGES - 1) e = NEDGES - 1;
                    svAll = srcs[e];
                    sv = __shfl(svAll, c, 64);
                    ei = r0n + c; if (ei > NEDGES - 1) ei = NEDGES - 1;
                }
                const short8* hrow = (const short8*)(h_bf + (long)sv * 64);
                const ushort* erow = eab_s + (long)ei * ECOLS;
                short8 N0 = hrow[q], N1 = hrow[4 + q];
                short8 N2 = *(const short8*)(erow + q * 8);
                short8 N3 = z8;
                if (q < 2) N3 = *(const short8*)(erow + 32 + q * 8);

                // ---- compute current chunk (operands already resident) ----
                f32x4 accf[4], accs[4];
                f32x4 z4 = {0.f, 0.f, 0.f, 0.f};
                __builtin_amdgcn_s_setprio(1);
                #pragma unroll
                for (int t = 0; t < 4; ++t) {
                    accf[t] = __builtin_amdgcn_mfma_f32_16x16x32_bf16(A0, B[t][0], z4, 0, 0, 0);
                    accs[t] = __builtin_amdgcn_mfma_f32_16x16x32_bf16(A0, B[t + 4][0], z4, 0, 0, 0);
                }
                #pragma unroll
                for (int t = 0; t < 4; ++t) {
                    accf[t] = __builtin_amdgcn_mfma_f32_16x16x32_bf16(A1, B[t][1], accf[t], 0, 0, 0);
                    accs[t] = __builtin_amdgcn_mfma_f32_16x16x32_bf16(A1, B[t + 4][1], accs[t], 0, 0, 0);
                }
                #pragma unroll
                for (int t = 0; t < 4; ++t) {
                    accf[t] = __builtin_amdgcn_mfma_f32_16x16x32_bf16(A2, B[t][2], accf[t], 0, 0, 0);
                    accs[t] = __builtin_amdgcn_mfma_f32_16x16x32_bf16(A2, B[t + 4][2], accs[t], 0, 0, 0);
                }
                #pragma unroll
                for (int t = 0; t < 4; ++t) {
                    accf[t] = __builtin_amdgcn_mfma_f32_16x16x32_bf16(A3, B[t][3], accf[t], 0, 0, 0);
                    accs[t] = __builtin_amdgcn_mfma_f32_16x16x32_bf16(A3, B[t + 4][3], accs[t], 0, 0, 0);
                }
                __builtin_amdgcn_s_setprio(0);

                int base = ci * 16 + q * 4;
                #pragma unroll
                for (int r = 0; r < 4; ++r) {
                    bool valid = (base + r) < d;
                    #pragma unroll
                    for (int t = 0; t < 4; ++t) {
                        float f = accf[t][r] + tf[t];
                        float s = accs[t][r] + ts[t];
                        float g = __builtin_amdgcn_rcpf(1.f + __expf(-f));
                        float sp = fmaxf(s, 0.f) + __logf(1.f + __expf(-fabsf(s)));
                        float msg = valid ? g * sp : 0.f;
                        if (t == 0) vs0 += msg;
                        else if (t == 1) vs1 += msg;
                        else if (t == 2) vs2 += msg;
                        else vs3 += msg;
                    }
                }
                A0 = N0; A1 = N1; A2 = N2; A3 = N3;
            }
        }
        vs0 += __shfl_xor(vs0, 16, 64); vs0 += __shfl_xor(vs0, 32, 64);
        vs1 += __shfl_xor(vs1, 16, 64); vs1 += __shfl_xor(vs1, 32, 64);
        vs2 += __shfl_xor(vs2, 16, 64); vs2 += __shfl_xor(vs2, 32, 64);
        vs3 += __shfl_xor(vs3, 16, 64); vs3 += __shfl_xor(vs3, 32, 64);
        float out = (q == 0) ? vs0 : (q == 1) ? vs1 : (q == 2) ? vs2 : vs3;
        agg[(long)tn * 64 + lane] = out;           // channel = q*16+c = lane
        float v = h[(long)tn * 64 + lane] + out;
        st1 += v;
        st2 = fmaf(v, v, st2);

        tn = tn2; r0 = r0n; r1 = r1n;
    }

    // block-level stats reduction -> 2 atomics/lane/block
    __shared__ float ls[4][64], lq[4][64];
    int w = threadIdx.x >> 6;
    ls[w][lane] = st1; lq[w][lane] = st2;
    __syncthreads();
    if (threadIdx.x < 64) {
        float t1 = ls[0][lane] + ls[1][lane] + ls[2][lane] + ls[3][lane];
        float t2 = lq[0][lane] + lq[1][lane] + lq[2][lane] + lq[3][lane];
        atomicAdd(&stats[lane], t1);
        atomicAdd(&stats[64 + lane], t2);
    }
}

// ---------------------------------------------------------------------------
// bnproj: BN apply (+ReLU) fused with NEXT layer's target projection.
// ---------------------------------------------------------------------------
__global__ __launch_bounds__(256) void bnproj(
    float* __restrict__ h, const float* __restrict__ agg,
    const float* __restrict__ stats, const float* __restrict__ gamma,
    const float* __restrict__ beta, ushort* __restrict__ h_bf,
    const ushort* __restrict__ Tpack_l, const float* __restrict__ bcf_l,
    const float* __restrict__ bcs_l, float* __restrict__ Ttgt) {
    int lane = threadIdx.x & 63;
    int cc = lane & 15;
    int g = lane >> 4;
    short8 Bf[4][2], Bs[4][2];
    #pragma unroll
    for (int t = 0; t < 4; ++t)
        #pragma unroll
        for (int ck = 0; ck < 2; ++ck) {
            Bf[t][ck] = *(const short8*)(Tpack_l + (t * 2 + ck) * 512 + lane * 8);
            Bs[t][ck] = *(const short8*)(Tpack_l + 4096 + (t * 2 + ck) * 512 + lane * 8);
        }
    float bfv[4], bsv[4];
    #pragma unroll
    for (int t = 0; t < 4; ++t) {
        bfv[t] = bcf_l[t * 16 + cc];
        bsv[t] = bcs_l[t * 16 + cc];
    }
    const float invn = 1.f / (float)NNODES;
    float sc[16], sh[16];
    #pragma unroll
    for (int m = 0; m < 16; ++m) {
        int ch = (m < 8) ? (g * 8 + m) : (32 + g * 8 + (m - 8));
        float mu = stats[ch] * invn;
        float va = stats[64 + ch] * invn - mu * mu;
        float s = rsqrtf(va + BN_EPS) * gamma[ch];
        sc[m] = s;
        sh[m] = beta[ch] - mu * s;
    }
    int wid = (blockIdx.x * blockDim.x + threadIdx.x) >> 6;
    int nw = (gridDim.x * blockDim.x) >> 6;
    for (int nb = wid; nb < NNODES / 16; nb += nw) {
        long base = (long)nb * 16;
        long row = base + cc;
        float* hr = h + row * 64;
        const float* ar = agg + row * 64;
        float y[16];
        #pragma unroll
        for (int half = 0; half < 2; ++half) {
            int col = half * 32 + g * 8;
            f32x4 hv0 = *(const f32x4*)(hr + col);
            f32x4 hv1 = *(const f32x4*)(hr + col + 4);
            f32x4 av0 = *(const f32x4*)(ar + col);
            f32x4 av1 = *(const f32x4*)(ar + col + 4);
            #pragma unroll
            for (int m = 0; m < 4; ++m) {
                float t0 = (hv0[m] + av0[m]) * sc[half * 8 + m] + sh[half * 8 + m];
                float t1 = (hv1[m] + av1[m]) * sc[half * 8 + 4 + m] + sh[half * 8 + 4 + m];
                y[half * 8 + m] = fmaxf(t0, 0.f);        // relu (layers 0,1 only)
                y[half * 8 + 4 + m] = fmaxf(t1, 0.f);
            }
        }
        f32x4 w0 = {y[0], y[1], y[2], y[3]},   w1 = {y[4], y[5], y[6], y[7]};
        f32x4 w2 = {y[8], y[9], y[10], y[11]}, w3 = {y[12], y[13], y[14], y[15]};
        *(f32x4*)(hr + g * 8) = w0;       *(f32x4*)(hr + g * 8 + 4) = w1;
        *(f32x4*)(hr + 32 + g * 8) = w2;  *(f32x4*)(hr + 32 + g * 8 + 4) = w3;
        uint u[8];
        #pragma unroll
        for (int m = 0; m < 8; ++m)
            u[m] = (uint)f2bf(y[m * 2]) | ((uint)f2bf(y[m * 2 + 1]) << 16);
        uint4 p0; p0.x = u[0]; p0.y = u[1]; p0.z = u[2]; p0.w = u[3];
        uint4 p1; p1.x = u[4]; p1.y = u[5]; p1.z = u[6]; p1.w = u[7];
        *(uint4*)(h_bf + row * 64 + g * 8) = p0;
        *(uint4*)(h_bf + row * 64 + 32 + g * 8) = p1;
        short8 A0 = *reinterpret_cast<short8*>(&p0);
        short8 A1 = *reinterpret_cast<short8*>(&p1);

        f32x4 accf[4], accs[4];
        f32x4 z4 = {0.f, 0.f, 0.f, 0.f};
        #pragma unroll
        for (int t = 0; t < 4; ++t) {
            accf[t] = __builtin_amdgcn_mfma_f32_16x16x32_bf16(A0, Bf[t][0], z4, 0, 0, 0);
            accs[t] = __builtin_amdgcn_mfma_f32_16x16x32_bf16(A0, Bs[t][0], z4, 0, 0, 0);
        }
        #pragma unroll
        for (int t = 0; t < 4; ++t) {
            accf[t] = __builtin_amdgcn_mfma_f32_16x16x32_bf16(A1, Bf[t][1], accf[t], 0, 0, 0);
            accs[t] = __builtin_amdgcn_mfma_f32_16x16x32_bf16(A1, Bs[t][1], accs[t], 0, 0, 0);
        }
        #pragma unroll
        for (int r = 0; r < 4; ++r) {
            long node = base + g * 4 + r;
            f32x4 vf = {accf[0][r] + bfv[0], accf[1][r] + bfv[1],
                        accf[2][r] + bfv[2], accf[3][r] + bfv[3]};
            f32x4 vs = {accs[0][r] + bsv[0], accs[1][r] + bsv[1],
                        accs[2][r] + bsv[2], accs[3][r] + bsv[3]};
            *(f32x4*)(Ttgt + node * 128 + cc * 4) = vf;
            *(f32x4*)(Ttgt + node * 128 + 64 + cc * 4) = vs;
        }
    }
}

// ---------------------------------------------------------------------------
// bn_final: last layer BN (no relu, no h_bf, no proj). Pure streaming.
// ---------------------------------------------------------------------------
__global__ __launch_bounds__(256) void bn_final(
    float* __restrict__ h, const float* __restrict__ agg,
    const float* __restrict__ stats, const float* __restrict__ gamma,
    const float* __restrict__ beta) {
    int tid = blockIdx.x * blockDim.x + threadIdx.x;
    int nth = gridDim.x * blockDim.x;   // multiple of 16
    const float invn = 1.f / (float)NNODES;
    int cb = (tid & 15) * 4;
    f32x4 sc, sh;
    #pragma unroll
    for (int j = 0; j < 4; ++j) {
        float m = stats[cb + j] * invn;
        float v = stats[64 + cb + j] * invn - m * m;
        float s = rsqrtf(v + BN_EPS) * gamma[cb + j];
        sc[j] = s;
        sh[j] = beta[cb + j] - m * s;
    }
    for (long i = tid; i < (long)NNODES * 16; i += nth) {
        f32x4 v = ((const f32x4*)h)[i];
        f32x4 a = ((const f32x4*)agg)[i];
        f32x4 y;
        #pragma unroll
        for (int j = 0; j < 4; ++j) y[j] = (v[j] + a[j]) * sc[j] + sh[j];
        ((f32x4*)h)[i] = y;
    }
}

extern "C" void kernel_launch(void* const* d_in, const int* in_sizes, int n_in,
                              void* d_out, int out_size, void* d_ws, size_t ws_size,
                              hipStream_t stream) {
    const float* x    = (const float*)d_in[0];
    const float* ea   = (const float*)d_in[1];
    const int*   eidx = (const int*)d_in[2];
    const float* W1   = (const float*)d_in[3];
    const float* b1   = (const float*)d_in[4];
    const float* W2   = (const float*)d_in[5];
    const float* b2   = (const float*)d_in[6];
    const float* Wf   = (const float*)d_in[7];
    const float* bf   = (const float*)d_in[8];
    const float* Ws   = (const float*)d_in[9];
    const float* bs   = (const float*)d_in[10];
    const float* gamma= (const float*)d_in[11];
    const float* beta = (const float*)d_in[12];
    float* h = (float*)d_out; // [NNODES, 64]

    // workspace layout (256 B aligned sections)
    char* wb = (char*)d_ws;
    auto align = [&]() { wb = (char*)(((size_t)wb + 255) & ~(size_t)255); };
    ushort* Bpack = (ushort*)wb;  wb += 3 * 8 * 4 * 512 * sizeof(ushort); align(); // 96 KB
    ushort* Tpack = (ushort*)wb;  wb += 3 * 2 * 4 * 2 * 512 * sizeof(ushort); align(); // 48 KB
    float* bcf   = (float*)wb;    wb += 3 * HID * sizeof(float);
    float* bcs   = (float*)wb;    wb += 3 * HID * sizeof(float);
    float* stats = (float*)wb;    wb += 3 * 2 * HID * sizeof(float); align();
    int* deg     = (int*)wb;      wb += NNODES * sizeof(int);
    int* rowptr  = (int*)wb;      wb += (NNODES + 1) * sizeof(int);
    int* cursor  = (int*)wb;      wb += NNODES * sizeof(int);
    int* bsum    = (int*)wb;      wb += 256 * sizeof(int);
    int* bbase   = (int*)wb;      wb += 256 * sizeof(int); align();
    int* srcs    = (int*)wb;      wb += NEDGES * sizeof(int);          // 3.2 MB
    align();
    float* Ttgt  = (float*)wb;    wb += (size_t)NNODES * 128 * sizeof(float); // 25.6 MB
    float* agg   = (float*)wb;    wb += (size_t)NNODES * HID * sizeof(float); // 12.8 MB
    ushort* h_bf = (ushort*)wb;   wb += (size_t)NNODES * HID * sizeof(ushort); // 6.4 MB
    ushort* eab_s= (ushort*)wb;   wb += (size_t)NEDGES * ECOLS * sizeof(ushort); // 76.8 MB

    // --- setup ---
    hipMemsetAsync(deg, 0, NNODES * sizeof(int), stream);
    prep_embed<<<EMBED_BASE + EMBED_BLOCKS, 256, 0, stream>>>(
        W2, b2, Wf, bf, Ws, bs, Bpack, Tpack, bcf, bcs, stats, deg, eidx,
        x, W1, b1, h, h_bf);
    k_blocksum<<<196, 256, 0, stream>>>(deg, bsum);
    k_scanbase<<<1, 256, 0, stream>>>(bsum, bbase, rowptr);
    k_writerow<<<196, 256, 0, stream>>>(deg, bbase, rowptr, cursor);
    scat_proj<<<SCAT_BLOCKS + PROJ_BLOCKS, 256, 0, stream>>>(
        eidx, cursor, srcs, ea, eab_s, h_bf, Tpack, bcf, bcs, Ttgt);

    for (int i = 0; i < 3; ++i) {
        edge_kernel<<<2048, 256, 0, stream>>>(eab_s, srcs, rowptr, h_bf, h, Ttgt,
                                              Bpack + i * 16384, agg, stats + i * 128);
        if (i < 2)
            bnproj<<<1024, 256, 0, stream>>>(h, agg, stats + i * 128, gamma + i * HID,
                                             beta + i * HID, h_bf,
                                             Tpack + (i + 1) * 8192,
                                             bcf + (i + 1) * HID, bcs + (i + 1) * HID,
                                             Ttgt);
        else
            bn_final<<<2048, 256, 0, stream>>>(h, agg, stats + i * 128,
                                               gamma + i * HID, beta + i * HID);
    }
}

// Round 10
// 731.483 us; speedup vs baseline: 2.8928x; 1.0444x over previous
//
#include <hip/hip_runtime.h>
#include <cmath>

#define NNODES 50000
#define NEDGES 800000
#define ORIG_FEA 92
#define NBR_FEA 41
#define HID 64
#define BN_EPS 1e-5f
#define ECOLS 48          // eab_s columns: 41 real + 7 pad

typedef __attribute__((ext_vector_type(8))) short short8;
typedef __attribute__((ext_vector_type(4))) float f32x4;
typedef unsigned short ushort;
typedef unsigned int uint;

static __device__ __forceinline__ ushort f2bf(float f) {
    uint u = __float_as_uint(f);
    uint r = u + 0x7fffu + ((u >> 16) & 1u);   // round-to-nearest-even
    return (ushort)(r >> 16);
}

// ---------------------------------------------------------------------------
// prep_embed: all input-only setup in ONE launch (deg zeroed by memset first).
//  blocks 0..23      : Bpack/Tpack/bias packing (6 groups x 4 quarters)
//  block  24         : zero BN stats
//  blocks 25..3149   : k_hist (800K edges, atomics on deg)
//  blocks 3150..4173 : embed h = x @ W1 + b1 (coalesced x load + shfl bcast)
// ---------------------------------------------------------------------------
#define HIST_BASE 25
#define HIST_BLOCKS 3125
#define EMBED_BASE (HIST_BASE + HIST_BLOCKS)   // 3150
#define EMBED_BLOCKS 1024

__global__ __launch_bounds__(256) void prep_embed(
    const float* __restrict__ W2, const float* __restrict__ b2,
    const float* __restrict__ Wf, const float* __restrict__ bf,
    const float* __restrict__ Ws, const float* __restrict__ bs,
    ushort* __restrict__ Bpack, ushort* __restrict__ Tpack,
    float* __restrict__ bcf, float* __restrict__ bcs,
    float* __restrict__ stats, int* __restrict__ deg,
    const int* __restrict__ eidx,
    const float* __restrict__ x, const float* __restrict__ W1,
    const float* __restrict__ b1, float* __restrict__ h,
    ushort* __restrict__ h_bf) {
    if (blockIdx.x >= EMBED_BASE) {
        int lane = threadIdx.x & 63;
        int wid = (((int)blockIdx.x - EMBED_BASE) * 256 + (int)threadIdx.x) >> 6;
        int nw = (EMBED_BLOCKS * 256) >> 6;
        float b1v = b1[lane];
        for (int n = wid; n < NNODES; n += nw) {
            const float* xr = x + (long)n * ORIG_FEA;
            float xa = xr[lane];
            float xb = (lane < ORIG_FEA - 64) ? xr[64 + lane] : 0.f;
            float a0 = b1v, a1 = 0.f, a2 = 0.f, a3 = 0.f;
            #pragma unroll
            for (int k = 0; k < 64; k += 4) {
                a0 = fmaf(__shfl(xa, k, 64),     W1[k * HID + lane], a0);
                a1 = fmaf(__shfl(xa, k + 1, 64), W1[(k + 1) * HID + lane], a1);
                a2 = fmaf(__shfl(xa, k + 2, 64), W1[(k + 2) * HID + lane], a2);
                a3 = fmaf(__shfl(xa, k + 3, 64), W1[(k + 3) * HID + lane], a3);
            }
            #pragma unroll
            for (int k = 0; k < ORIG_FEA - 64; k += 4) {
                a0 = fmaf(__shfl(xb, k, 64),     W1[(64 + k) * HID + lane], a0);
                a1 = fmaf(__shfl(xb, k + 1, 64), W1[(65 + k) * HID + lane], a1);
                a2 = fmaf(__shfl(xb, k + 2, 64), W1[(66 + k) * HID + lane], a2);
                a3 = fmaf(__shfl(xb, k + 3, 64), W1[(67 + k) * HID + lane], a3);
            }
            float acc = (a0 + a1) + (a2 + a3);
            h[(long)n * HID + lane] = acc;
            h_bf[(long)n * HID + lane] = f2bf(acc);
        }
        return;
    }
    if (blockIdx.x >= HIST_BASE) {
        int e = ((int)blockIdx.x - HIST_BASE) * 256 + (int)threadIdx.x;
        if (e < NEDGES) atomicAdd(&deg[eidx[NEDGES + e]], 1);
        return;
    }
    if (blockIdx.x == 24) {
        for (int i = threadIdx.x; i < 3 * 128; i += blockDim.x) stats[i] = 0.f;
        return;
    }
    // blocks 0..23: weight packing
    int group = blockIdx.x >> 2;       // 0..5 = (layer, fs)
    int quarter = blockIdx.x & 3;
    int layer = group >> 1;
    int fs = group & 1;
    const float* Wbig = (fs ? Ws : Wf) + layer * 192 * HID;
    const float* We = Wbig + 128 * HID;                 // e-part rows
    const float* bvec = (fs ? bs : bf) + layer * HID;
    float* bc = (fs ? bcs : bcf) + layer * HID;
    ushort* Bp = Bpack + layer * 16384 + fs * 8192;     // t = fs*4 + tt
    ushort* Tp = Tpack + layer * 8192 + fs * 4096;

    for (int idx = quarter * 2048 + threadIdx.x; idx < (quarter + 1) * 2048;
         idx += blockDim.x) {
        int j = idx & 7;
        int lane = (idx >> 3) & 63;
        int ck = (idx >> 9) & 3;
        int tt = (idx >> 11) & 3;
        int k = ck * 32 + ((lane >> 4) * 8) + j;
        int col = tt * 16 + (lane & 15);
        float v = 0.f;
        if (k < 64) v = Wbig[(64 + k) * HID + col];
        else if (k < 64 + NBR_FEA) {
            int r = k - 64;
            float a = 0.f;
            for (int m = 0; m < HID; ++m) a += W2[r * HID + m] * We[m * HID + col];
            v = a;
        }
        Bp[(tt * 4 + ck) * 512 + lane * 8 + j] = f2bf(v);
    }
    // target-block B fragments (K=64), quarter-split
    for (int idx = quarter * 1024 + threadIdx.x; idx < (quarter + 1) * 1024;
         idx += blockDim.x) {
        int j = idx & 7;
        int lane = (idx >> 3) & 63;
        int ck = (idx >> 9) & 1;
        int t = (idx >> 10) & 3;
        int k = ck * 32 + ((lane >> 4) * 8) + j;
        int col = t * 16 + (lane & 15);
        Tp[(t * 2 + ck) * 512 + lane * 8 + j] = f2bf(Wbig[k * HID + col]);
    }
    if (quarter == 3) {
        for (int c0 = threadIdx.x; c0 < HID; c0 += blockDim.x) {
            float a = bvec[c0];
            for (int m = 0; m < HID; ++m) a += b2[m] * We[m * HID + c0];
            bc[c0] = a;
        }
    }
}

// ---------------------------------------------------------------------------
// CSR scan kernels
// ---------------------------------------------------------------------------
__global__ void k_blocksum(const int* __restrict__ deg, int* __restrict__ bsum) {
    __shared__ int sh[256];
    int i = blockIdx.x * 256 + threadIdx.x;
    sh[threadIdx.x] = (i < NNODES) ? deg[i] : 0;
    __syncthreads();
    for (int s = 128; s > 0; s >>= 1) {
        if (threadIdx.x < s) sh[threadIdx.x] += sh[threadIdx.x + s];
        __syncthreads();
    }
    if (threadIdx.x == 0) bsum[blockIdx.x] = sh[0];
}

__global__ void k_scanbase(const int* __restrict__ bsum, int* __restrict__ bbase,
                           int* __restrict__ rowptr) {
    __shared__ int sh[256];
    int t = threadIdx.x;
    int v = (t < 196) ? bsum[t] : 0;
    sh[t] = v;
    __syncthreads();
    for (int s = 1; s < 256; s <<= 1) {
        int add = (t >= s) ? sh[t - s] : 0;
        __syncthreads();
        sh[t] += add;
        __syncthreads();
    }
    if (t < 196) bbase[t] = sh[t] - v;   // exclusive
    if (t == 0) rowptr[NNODES] = NEDGES;
}

__global__ void k_writerow(const int* __restrict__ deg, const int* __restrict__ bbase,
                           int* __restrict__ rowptr, int* __restrict__ cursor) {
    __shared__ int sh[256];
    int t = threadIdx.x;
    int i = blockIdx.x * 256 + t;
    int v = (i < NNODES) ? deg[i] : 0;
    sh[t] = v;
    __syncthreads();
    for (int s = 1; s < 256; s <<= 1) {
        int add = (t >= s) ? sh[t - s] : 0;
        __syncthreads();
        sh[t] += add;
        __syncthreads();
    }
    if (i < NNODES) {
        int e = bbase[blockIdx.x] + sh[t] - v;
        rowptr[i] = e;
        cursor[i] = e;
    }
}

// ---------------------------------------------------------------------------
// scat_proj: one launch, two independent jobs.
//  blocks < 3125 : CSR scatter + eab row build (thread-per-edge; 41 ea loads
//                  issued before the atomic; 96 B row write to slot pos)
//  blocks >= 3125: layer-0 proj_mfma (Ttgt = h_bf @ W_tgt + bc)
// ---------------------------------------------------------------------------
#define SCAT_BLOCKS 3125
#define PROJ_BLOCKS 1024

__global__ __launch_bounds__(256) void scat_proj(
    const int* __restrict__ eidx, int* __restrict__ cursor,
    int* __restrict__ srcs, const float* __restrict__ ea,
    ushort* __restrict__ eab_s,
    const ushort* __restrict__ h_bf, const ushort* __restrict__ Tpack_l,
    const float* __restrict__ bcf_l, const float* __restrict__ bcs_l,
    float* __restrict__ Ttgt) {
    if (blockIdx.x < SCAT_BLOCKS) {
        int e = blockIdx.x * 256 + threadIdx.x;
        if (e >= NEDGES) return;
        const float* row = ea + (long)e * NBR_FEA;
        float a[NBR_FEA];
        #pragma unroll
        for (int k = 0; k < NBR_FEA; ++k) a[k] = row[k];
        int tgt = eidx[NEDGES + e];
        int pos = atomicAdd(&cursor[tgt], 1);
        srcs[pos] = eidx[e];
        uint u[24];
        #pragma unroll
        for (int m = 0; m < 20; ++m)
            u[m] = (uint)f2bf(a[2 * m]) | ((uint)f2bf(a[2 * m + 1]) << 16);
        u[20] = (uint)f2bf(a[40]);
        u[21] = 0u; u[22] = 0u; u[23] = 0u;
        uint4* dst = (uint4*)(eab_s + (long)pos * ECOLS);
        #pragma unroll
        for (int m = 0; m < 6; ++m) {
            uint4 o; o.x = u[4 * m]; o.y = u[4 * m + 1];
            o.z = u[4 * m + 2]; o.w = u[4 * m + 3];
            dst[m] = o;
        }
        return;
    }
    // ---- proj branch ----
    int lane = threadIdx.x & 63;
    int cc = lane & 15;
    int g = lane >> 4;
    short8 Bf[4][2], Bs[4][2];
    #pragma unroll
    for (int t = 0; t < 4; ++t)
        #pragma unroll
        for (int ck = 0; ck < 2; ++ck) {
            Bf[t][ck] = *(const short8*)(Tpack_l + (t * 2 + ck) * 512 + lane * 8);
            Bs[t][ck] = *(const short8*)(Tpack_l + 4096 + (t * 2 + ck) * 512 + lane * 8);
        }
    float bfv[4], bsv[4];
    #pragma unroll
    for (int t = 0; t < 4; ++t) {
        bfv[t] = bcf_l[t * 16 + cc];
        bsv[t] = bcs_l[t * 16 + cc];
    }
    int wid = (((int)blockIdx.x - SCAT_BLOCKS) * 256 + (int)threadIdx.x) >> 6;
    int nw = (PROJ_BLOCKS * 256) >> 6;
    for (int nb = wid; nb < NNODES / 16; nb += nw) {
        long base = (long)nb * 16;
        long row = base + cc;
        short8 A0 = *(const short8*)(h_bf + row * 64 + g * 8);
        short8 A1 = *(const short8*)(h_bf + row * 64 + 32 + g * 8);
        f32x4 accf[4], accs[4];
        f32x4 z4 = {0.f, 0.f, 0.f, 0.f};
        #pragma unroll
        for (int t = 0; t < 4; ++t) {
            accf[t] = __builtin_amdgcn_mfma_f32_16x16x32_bf16(A0, Bf[t][0], z4, 0, 0, 0);
            accs[t] = __builtin_amdgcn_mfma_f32_16x16x32_bf16(A0, Bs[t][0], z4, 0, 0, 0);
        }
        #pragma unroll
        for (int t = 0; t < 4; ++t) {
            accf[t] = __builtin_amdgcn_mfma_f32_16x16x32_bf16(A1, Bf[t][1], accf[t], 0, 0, 0);
            accs[t] = __builtin_amdgcn_mfma_f32_16x16x32_bf16(A1, Bs[t][1], accs[t], 0, 0, 0);
        }
        #pragma unroll
        for (int r = 0; r < 4; ++r) {
            long node = base + g * 4 + r;
            f32x4 vf = {accf[0][r] + bfv[0], accf[1][r] + bfv[1],
                        accf[2][r] + bfv[2], accf[3][r] + bfv[3]};
            f32x4 vs = {accs[0][r] + bsv[0], accs[1][r] + bsv[1],
                        accs[2][r] + bsv[2], accs[3][r] + bsv[3]};
            *(f32x4*)(Ttgt + node * 128 + cc * 4) = vf;
            *(f32x4*)(Ttgt + node * 128 + 64 + cc * 4) = vs;
        }
    }
}

// ---------------------------------------------------------------------------
// Edge kernel: one wave per target, chunk-ahead pipeline, B register-resident
// (proven structure). THIS ROUND:
//  - grid = 512 blocks = exactly the 2-waves/SIMD residency (2048 waves).
//    Every wave amortizes its 32 KB Bpack load over 24.4 targets instead of
//    6.1, and there is a single residency generation (no churn).
//  - agg buffer eliminated: each target is owned by one wave, so the
//    residual update h[tn] += out is done in place (same arithmetic).
// ---------------------------------------------------------------------------
__global__ __launch_bounds__(256, 2) void edge_kernel(
    const ushort* __restrict__ eab_s, const int* __restrict__ srcs,
    const int* __restrict__ rowptr, const ushort* __restrict__ h_bf,
    float* __restrict__ h, const float* __restrict__ Ttgt,
    const ushort* __restrict__ Bpack, float* __restrict__ stats) {
    int lane = threadIdx.x & 63;
    int q = lane >> 4;
    int c = lane & 15;
    int wid = (blockIdx.x * blockDim.x + threadIdx.x) >> 6;
    int nw = (gridDim.x * blockDim.x) >> 6;
    const short8 z8 = {0, 0, 0, 0, 0, 0, 0, 0};

    short8 B[8][4];
    #pragma unroll
    for (int t = 0; t < 8; ++t)
        #pragma unroll
        for (int ck = 0; ck < 4; ++ck)
            B[t][ck] = *(const short8*)(Bpack + ((t * 4 + ck) * 512 + lane * 8));

    float st1 = 0.f, st2 = 0.f;
    int tn = wid;
    int r0 = 0, r1 = 0, svAll = 0;
    short8 A0, A1, A2, A3;
    if (tn < NNODES) {
        r0 = rowptr[tn]; r1 = rowptr[tn + 1];
        int e = r0 + lane; if (e > NEDGES - 1) e = NEDGES - 1;
        svAll = srcs[e];
        int sv = __shfl(svAll, c, 64);
        int ei = r0 + c; if (ei > NEDGES - 1) ei = NEDGES - 1;
        const short8* hrow = (const short8*)(h_bf + (long)sv * 64);
        const ushort* erow = eab_s + (long)ei * ECOLS;
        A0 = hrow[q]; A1 = hrow[4 + q];
        A2 = *(const short8*)(erow + q * 8);
        A3 = z8;
        if (q < 2) A3 = *(const short8*)(erow + 32 + q * 8);
    }

    while (tn < NNODES) {
        int tn2 = tn + nw;
        int r0n = 0, r1n = 0;
        if (tn2 < NNODES) { r0n = rowptr[tn2]; r1n = rowptr[tn2 + 1]; }
        f32x4 tf = *(const f32x4*)(Ttgt + (long)tn * 128 + 4 * c);
        f32x4 ts = *(const f32x4*)(Ttgt + (long)tn * 128 + 64 + 4 * c);
        int d = r1 - r0;
        int nch = (d + 15) >> 4;
        float vs0 = 0.f, vs1 = 0.f, vs2 = 0.f, vs3 = 0.f;

        if (nch == 0) {
            // isolated node: still prefetch next target's chunk 0
            int e = r0n + lane; if (e > NEDGES - 1) e = NEDGES - 1;
            svAll = srcs[e];
            int sv = __shfl(svAll, c, 64);
            int ei = r0n + c; if (ei > NEDGES - 1) ei = NEDGES - 1;
            const short8* hrow = (const short8*)(h_bf + (long)sv * 64);
            const ushort* erow = eab_s + (long)ei * ECOLS;
            A0 = hrow[q]; A1 = hrow[4 + q];
            A2 = *(const short8*)(erow + q * 8);
            A3 = z8;
            if (q < 2) A3 = *(const short8*)(erow + 32 + q * 8);
        } else {
            for (int ci = 0; ci < nch; ++ci) {
                // ---- issue prefetch for chunk ci+1 (or next target's chunk 0)
                int sv, ei;
                int nidx = ci + 1;
                if (nidx < nch) {
                    if ((nidx & 3) == 0) {       // superchunk boundary (d>64, rare)
                        int e = r0 + nidx * 16 + lane;
                        if (e > NEDGES - 1) e = NEDGES - 1;
                        svAll = srcs[e];
                    }
                    sv = __shfl(svAll, ((nidx & 3) << 4) + c, 64);
                    ei = r0 + nidx * 16 + c;
                    if (ei > NEDGES - 1) ei = NEDGES - 1;
                } else {
                    int e = r0n + lane; if (e > NEDGES - 1) e = NEDGES - 1;
                    svAll = srcs[e];
                    sv = __shfl(svAll, c, 64);
                    ei = r0n + c; if (ei > NEDGES - 1) ei = NEDGES - 1;
                }
                const short8* hrow = (const short8*)(h_bf + (long)sv * 64);
                const ushort* erow = eab_s + (long)ei * ECOLS;
                short8 N0 = hrow[q], N1 = hrow[4 + q];
                short8 N2 = *(const short8*)(erow + q * 8);
                short8 N3 = z8;
                if (q < 2) N3 = *(const short8*)(erow + 32 + q * 8);

                // ---- compute current chunk (operands already resident) ----
                f32x4 accf[4], accs[4];
                f32x4 z4 = {0.f, 0.f, 0.f, 0.f};
                __builtin_amdgcn_s_setprio(1);
                #pragma unroll
                for (int t = 0; t < 4; ++t) {
                    accf[t] = __builtin_amdgcn_mfma_f32_16x16x32_bf16(A0, B[t][0], z4, 0, 0, 0);
                    accs[t] = __builtin_amdgcn_mfma_f32_16x16x32_bf16(A0, B[t + 4][0], z4, 0, 0, 0);
                }
                #pragma unroll
                for (int t = 0; t < 4; ++t) {
                    accf[t] = __builtin_amdgcn_mfma_f32_16x16x32_bf16(A1, B[t][1], accf[t], 0, 0, 0);
                    accs[t] = __builtin_amdgcn_mfma_f32_16x16x32_bf16(A1, B[t + 4][1], accs[t], 0, 0, 0);
                }
                #pragma unroll
                for (int t = 0; t < 4; ++t) {
                    accf[t] = __builtin_amdgcn_mfma_f32_16x16x32_bf16(A2, B[t][2], accf[t], 0, 0, 0);
                    accs[t] = __builtin_amdgcn_mfma_f32_16x16x32_bf16(A2, B[t + 4][2], accs[t], 0, 0, 0);
                }
                #pragma unroll
                for (int t = 0; t < 4; ++t) {
                    accf[t] = __builtin_amdgcn_mfma_f32_16x16x32_bf16(A3, B[t][3], accf[t], 0, 0, 0);
                    accs[t] = __builtin_amdgcn_mfma_f32_16x16x32_bf16(A3, B[t + 4][3], accs[t], 0, 0, 0);
                }
                __builtin_amdgcn_s_setprio(0);

                int base = ci * 16 + q * 4;
                #pragma unroll
                for (int r = 0; r < 4; ++r) {
                    bool valid = (base + r) < d;
                    #pragma unroll
                    for (int t = 0; t < 4; ++t) {
                        float f = accf[t][r] + tf[t];
                        float s = accs[t][r] + ts[t];
                        float g = __builtin_amdgcn_rcpf(1.f + __expf(-f));
                        float sp = fmaxf(s, 0.f) + __logf(1.f + __expf(-fabsf(s)));
                        float msg = valid ? g * sp : 0.f;
                        if (t == 0) vs0 += msg;
                        else if (t == 1) vs1 += msg;
                        else if (t == 2) vs2 += msg;
                        else vs3 += msg;
                    }
                }
                A0 = N0; A1 = N1; A2 = N2; A3 = N3;
            }
        }
        vs0 += __shfl_xor(vs0, 16, 64); vs0 += __shfl_xor(vs0, 32, 64);
        vs1 += __shfl_xor(vs1, 16, 64); vs1 += __shfl_xor(vs1, 32, 64);
        vs2 += __shfl_xor(vs2, 16, 64); vs2 += __shfl_xor(vs2, 32, 64);
        vs3 += __shfl_xor(vs3, 16, 64); vs3 += __shfl_xor(vs3, 32, 64);
        float out = (q == 0) ? vs0 : (q == 1) ? vs1 : (q == 2) ? vs2 : vs3;
        float v = h[(long)tn * 64 + lane] + out;   // residual, in place
        h[(long)tn * 64 + lane] = v;
        st1 += v;
        st2 = fmaf(v, v, st2);

        tn = tn2; r0 = r0n; r1 = r1n;
    }

    // block-level stats reduction -> 2 atomics/lane/block
    __shared__ float ls[4][64], lq[4][64];
    int w = threadIdx.x >> 6;
    ls[w][lane] = st1; lq[w][lane] = st2;
    __syncthreads();
    if (threadIdx.x < 64) {
        float t1 = ls[0][lane] + ls[1][lane] + ls[2][lane] + ls[3][lane];
        float t2 = lq[0][lane] + lq[1][lane] + lq[2][lane] + lq[3][lane];
        atomicAdd(&stats[lane], t1);
        atomicAdd(&stats[64 + lane], t2);
    }
}

// ---------------------------------------------------------------------------
// bnproj: BN apply (+ReLU) fused with NEXT layer's target projection.
// h already contains the residual sum (edge_kernel updates in place).
// ---------------------------------------------------------------------------
__global__ __launch_bounds__(256) void bnproj(
    float* __restrict__ h,
    const float* __restrict__ stats, const float* __restrict__ gamma,
    const float* __restrict__ beta, ushort* __restrict__ h_bf,
    const ushort* __restrict__ Tpack_l, const float* __restrict__ bcf_l,
    const float* __restrict__ bcs_l, float* __restrict__ Ttgt) {
    int lane = threadIdx.x & 63;
    int cc = lane & 15;
    int g = lane >> 4;
    short8 Bf[4][2], Bs[4][2];
    #pragma unroll
    for (int t = 0; t < 4; ++t)
        #pragma unroll
        for (int ck = 0; ck < 2; ++ck) {
            Bf[t][ck] = *(const short8*)(Tpack_l + (t * 2 + ck) * 512 + lane * 8);
            Bs[t][ck] = *(const short8*)(Tpack_l + 4096 + (t * 2 + ck) * 512 + lane * 8);
        }
    float bfv[4], bsv[4];
    #pragma unroll
    for (int t = 0; t < 4; ++t) {
        bfv[t] = bcf_l[t * 16 + cc];
        bsv[t] = bcs_l[t * 16 + cc];
    }
    const float invn = 1.f / (float)NNODES;
    float sc[16], sh[16];
    #pragma unroll
    for (int m = 0; m < 16; ++m) {
        int ch = (m < 8) ? (g * 8 + m) : (32 + g * 8 + (m - 8));
        float mu = stats[ch] * invn;
        float va = stats[64 + ch] * invn - mu * mu;
        float s = rsqrtf(va + BN_EPS) * gamma[ch];
        sc[m] = s;
        sh[m] = beta[ch] - mu * s;
    }
    int wid = (blockIdx.x * blockDim.x + threadIdx.x) >> 6;
    int nw = (gridDim.x * blockDim.x) >> 6;
    for (int nb = wid; nb < NNODES / 16; nb += nw) {
        long base = (long)nb * 16;
        long row = base + cc;
        float* hr = h + row * 64;
        float y[16];
        #pragma unroll
        for (int half = 0; half < 2; ++half) {
            int col = half * 32 + g * 8;
            f32x4 hv0 = *(const f32x4*)(hr + col);
            f32x4 hv1 = *(const f32x4*)(hr + col + 4);
            #pragma unroll
            for (int m = 0; m < 4; ++m) {
                float t0 = hv0[m] * sc[half * 8 + m] + sh[half * 8 + m];
                float t1 = hv1[m] * sc[half * 8 + 4 + m] + sh[half * 8 + 4 + m];
                y[half * 8 + m] = fmaxf(t0, 0.f);        // relu (layers 0,1 only)
                y[half * 8 + 4 + m] = fmaxf(t1, 0.f);
            }
        }
        f32x4 w0 = {y[0], y[1], y[2], y[3]},   w1 = {y[4], y[5], y[6], y[7]};
        f32x4 w2 = {y[8], y[9], y[10], y[11]}, w3 = {y[12], y[13], y[14], y[15]};
        *(f32x4*)(hr + g * 8) = w0;       *(f32x4*)(hr + g * 8 + 4) = w1;
        *(f32x4*)(hr + 32 + g * 8) = w2;  *(f32x4*)(hr + 32 + g * 8 + 4) = w3;
        uint u[8];
        #pragma unroll
        for (int m = 0; m < 8; ++m)
            u[m] = (uint)f2bf(y[m * 2]) | ((uint)f2bf(y[m * 2 + 1]) << 16);
        uint4 p0; p0.x = u[0]; p0.y = u[1]; p0.z = u[2]; p0.w = u[3];
        uint4 p1; p1.x = u[4]; p1.y = u[5]; p1.z = u[6]; p1.w = u[7];
        *(uint4*)(h_bf + row * 64 + g * 8) = p0;
        *(uint4*)(h_bf + row * 64 + 32 + g * 8) = p1;
        short8 A0 = *reinterpret_cast<short8*>(&p0);
        short8 A1 = *reinterpret_cast<short8*>(&p1);

        f32x4 accf[4], accs[4];
        f32x4 z4 = {0.f, 0.f, 0.f, 0.f};
        #pragma unroll
        for (int t = 0; t < 4; ++t) {
            accf[t] = __builtin_amdgcn_mfma_f32_16x16x32_bf16(A0, Bf[t][0], z4, 0, 0, 0);
            accs[t] = __builtin_amdgcn_mfma_f32_16x16x32_bf16(A0, Bs[t][0], z4, 0, 0, 0);
        }
        #pragma unroll
        for (int t = 0; t < 4; ++t) {
            accf[t] = __builtin_amdgcn_mfma_f32_16x16x32_bf16(A1, Bf[t][1], accf[t], 0, 0, 0);
            accs[t] = __builtin_amdgcn_mfma_f32_16x16x32_bf16(A1, Bs[t][1], accs[t], 0, 0, 0);
        }
        #pragma unroll
        for (int r = 0; r < 4; ++r) {
            long node = base + g * 4 + r;
            f32x4 vf = {accf[0][r] + bfv[0], accf[1][r] + bfv[1],
                        accf[2][r] + bfv[2], accf[3][r] + bfv[3]};
            f32x4 vs = {accs[0][r] + bsv[0], accs[1][r] + bsv[1],
                        accs[2][r] + bsv[2], accs[3][r] + bsv[3]};
            *(f32x4*)(Ttgt + node * 128 + cc * 4) = vf;
            *(f32x4*)(Ttgt + node * 128 + 64 + cc * 4) = vs;
        }
    }
}

// ---------------------------------------------------------------------------
// bn_final: last layer BN (no relu, no h_bf, no proj). Pure streaming.
// h already contains the residual sum.
// ---------------------------------------------------------------------------
__global__ __launch_bounds__(256) void bn_final(
    float* __restrict__ h,
    const float* __restrict__ stats, const float* __restrict__ gamma,
    const float* __restrict__ beta) {
    int tid = blockIdx.x * blockDim.x + threadIdx.x;
    int nth = gridDim.x * blockDim.x;   // multiple of 16
    const float invn = 1.f / (float)NNODES;
    int cb = (tid & 15) * 4;
    f32x4 sc, sh;
    #pragma unroll
    for (int j = 0; j < 4; ++j) {
        float m = stats[cb + j] * invn;
        float v = stats[64 + cb + j] * invn - m * m;
        float s = rsqrtf(v + BN_EPS) * gamma[cb + j];
        sc[j] = s;
        sh[j] = beta[cb + j] - m * s;
    }
    for (long i = tid; i < (long)NNODES * 16; i += nth) {
        f32x4 v = ((const f32x4*)h)[i];
        f32x4 y;
        #pragma unroll
        for (int j = 0; j < 4; ++j) y[j] = v[j] * sc[j] + sh[j];
        ((f32x4*)h)[i] = y;
    }
}

extern "C" void kernel_launch(void* const* d_in, const int* in_sizes, int n_in,
                              void* d_out, int out_size, void* d_ws, size_t ws_size,
                              hipStream_t stream) {
    const float* x    = (const float*)d_in[0];
    const float* ea   = (const float*)d_in[1];
    const int*   eidx = (const int*)d_in[2];
    const float* W1   = (const float*)d_in[3];
    const float* b1   = (const float*)d_in[4];
    const float* W2   = (const float*)d_in[5];
    const float* b2   = (const float*)d_in[6];
    const float* Wf   = (const float*)d_in[7];
    const float* bf   = (const float*)d_in[8];
    const float* Ws   = (const float*)d_in[9];
    const float* bs   = (const float*)d_in[10];
    const float* gamma= (const float*)d_in[11];
    const float* beta = (const float*)d_in[12];
    float* h = (float*)d_out; // [NNODES, 64]

    // workspace layout (256 B aligned sections)
    char* wb = (char*)d_ws;
    auto align = [&]() { wb = (char*)(((size_t)wb + 255) & ~(size_t)255); };
    ushort* Bpack = (ushort*)wb;  wb += 3 * 8 * 4 * 512 * sizeof(ushort); align(); // 96 KB
    ushort* Tpack = (ushort*)wb;  wb += 3 * 2 * 4 * 2 * 512 * sizeof(ushort); align(); // 48 KB
    float* bcf   = (float*)wb;    wb += 3 * HID * sizeof(float);
    float* bcs   = (float*)wb;    wb += 3 * HID * sizeof(float);
    float* stats = (float*)wb;    wb += 3 * 2 * HID * sizeof(float); align();
    int* deg     = (int*)wb;      wb += NNODES * sizeof(int);
    int* rowptr  = (int*)wb;      wb += (NNODES + 1) * sizeof(int);
    int* cursor  = (int*)wb;      wb += NNODES * sizeof(int);
    int* bsum    = (int*)wb;      wb += 256 * sizeof(int);
    int* bbase   = (int*)wb;      wb += 256 * sizeof(int); align();
    int* srcs    = (int*)wb;      wb += NEDGES * sizeof(int);          // 3.2 MB
    align();
    float* Ttgt  = (float*)wb;    wb += (size_t)NNODES * 128 * sizeof(float); // 25.6 MB
    ushort* h_bf = (ushort*)wb;   wb += (size_t)NNODES * HID * sizeof(ushort); // 6.4 MB
    ushort* eab_s= (ushort*)wb;   wb += (size_t)NEDGES * ECOLS * sizeof(ushort); // 76.8 MB

    // --- setup ---
    hipMemsetAsync(deg, 0, NNODES * sizeof(int), stream);
    prep_embed<<<EMBED_BASE + EMBED_BLOCKS, 256, 0, stream>>>(
        W2, b2, Wf, bf, Ws, bs, Bpack, Tpack, bcf, bcs, stats, deg, eidx,
        x, W1, b1, h, h_bf);
    k_blocksum<<<196, 256, 0, stream>>>(deg, bsum);
    k_scanbase<<<1, 256, 0, stream>>>(bsum, bbase, rowptr);
    k_writerow<<<196, 256, 0, stream>>>(deg, bbase, rowptr, cursor);
    scat_proj<<<SCAT_BLOCKS + PROJ_BLOCKS, 256, 0, stream>>>(
        eidx, cursor, srcs, ea, eab_s, h_bf, Tpack, bcf, bcs, Ttgt);

    for (int i = 0; i < 3; ++i) {
        edge_kernel<<<512, 256, 0, stream>>>(eab_s, srcs, rowptr, h_bf, h, Ttgt,
                                             Bpack + i * 16384, stats + i * 128);
        if (i < 2)
            bnproj<<<1024, 256, 0, stream>>>(h, stats + i * 128, gamma + i * HID,
                                             beta + i * HID, h_bf,
                                             Tpack + (i + 1) * 8192,
                                             bcf + (i + 1) * HID, bcs + (i + 1) * HID,
                                             Ttgt);
        else
            bn_final<<<2048, 256, 0, stream>>>(h, stats + i * 128,
                                               gamma + i * HID, beta + i * HID);
    }
}